// Round 8
// baseline (419.638 us; speedup 1.0000x reference)
//
#include <hip/hip_runtime.h>
#include <math.h>

// ---------------------------------------------------------------------------
// Problem constants
// ---------------------------------------------------------------------------
#define DM    256     // D_MODEL
#define NH    4
#define HD    64
#define TS    40
#define TM1   39
#define BB    32
#define DFF   1024
#define DINO  384
#define NPATCH 256
#define VOCAB 4096

#define NTOK  24960   // 780*32 packed (t, p<=t, b) tokens
#define NQ2   1248    // 39*32

typedef _Float16 f16;
typedef __attribute__((ext_vector_type(8))) _Float16 half8;  // MFMA A/B frag
typedef __attribute__((ext_vector_type(4))) _Float16 half4;
typedef __attribute__((ext_vector_type(4))) float f32x4;

// ---------------------------------------------------------------------------
// Workspace layout (float offsets), 127.25 MB total (< 127.57 proven budget).
// ROUND-17: f16 activation chain (x1p/x1h/h1p/h1h) — verified r5.
// ROUND-18: out-proj0 & lin2 -> BM=128 — verified r6 (left top-5).
// ROUND-19: final_out 8-wave restructure (see kernel comment).
// ---------------------------------------------------------------------------
#define OFF_EMBH   0u          /* f16 1280*256  = 327680 h -> 163840 fl */
#define OFF_EMB    163840u     /* f32 1280*256  -> 327680 fl (dead; kept) */
#define OFF_QKVH   491520u     /* f16 1280*768  = 983040 h -> 491520 fl */
#define OFF_X1     983040u     /* x1p: f16 24960*256 (pre-LN attn-block out) */
#define OFF_X1H    7372800u    /* f16 24960*256 (ln1 out); pph aliases head */
#define OFF_H1     10567680u   /* h1p: f16 24960*256 (pre-LN ffn out) */
#define OFF_BIG    16957440u   /* 12779520 fl */
/* big interior (float offsets from big):
     head [0,6389760)         : ao0h (attn0..outproj0) / ff1h spans ALL of big
                                (lin1..lin2) / kv1h (kv..attn1)
     BT_AO1H  [6389760,6553600)   f16 1280*256, written by attn1
     BT_X2    [6553600,6881280)   f32 1280*256, written by out-proj1
     BT_X2H   [6881280,7045120)   f16 1280*256, written by ln(x2)
     BT_FF2H  [7045120,7700480)   f16 1280*1024, written by lin1-l1
     BT_H1H   [7700480,10895360)  f16 24960*256, written by ln2 (post-lin2),
                                  read by kv-gemm/attn1/ln-x2 residual. */
#define   BT_AO1H  6389760u
#define   BT_X2    6553600u
#define   BT_X2H   6881280u
#define   BT_FF2H  7045120u
#define   BT_H1H   7700480u
#define OFF_CTX    29736960u   /* f32 1280*256 -> 327680 fl (rows 0..31 zeroed by prep) */
#define OFF_CPB    30064640u   /* f32 1280*256 (lin2-l1 pad spill lands here; rewritten) */
#define OFF_U      30392320u   /* f32 1280*256 (dedicated) */
#define OFF_S      30720000u   /* f32 2048 fl */
#define OFF_WQKVH  30722048u   /* f16 768*256 */
#define OFF_WQ1H   30820352u   /* f16 256*256 */
#define OFF_KVWH   30853120u   /* f16 512*256 */
#define OFF_WOH    30918656u   /* f16 256*256 */
#define OFF_WOH1   30951424u   /* f16 256*256 */
#define OFF_L1WH   30984192u   /* f16 1024*256 */
#define OFF_L1WH1  31115264u   /* f16 1024*256 */
#define OFF_L2WH   31246336u   /* f16 256*1024 */
#define OFF_L2WH1  31377408u   /* f16 256*1024 */
#define OFF_W1PH   31508480u   /* f16 256*384 */
#define OFF_W1CH   31557632u   /* f16 256*256 */
#define OFF_FW2TH  31590400u   /* f16 256*256 */
#define OFF_CWGH   31623168u   /* f16 1280*256 */
#define OFF_MAP    31787008u   /* int 24960+1248 */
#define WS_FLOATS  31813216u   /* = 127.25 MB < 127.57 known-good */

// ---------------------------------------------------------------------------
// prep: embed | all weight f16 conversions | w1p/w1c/fw2t gathers | cls
// gather | s vector | ctx t=0 zeros | maps.
// ---------------------------------------------------------------------------
__global__ __launch_bounds__(256) void prep_kernel(
    const int* __restrict__ tokens, const float* __restrict__ etab,
    const float* __restrict__ pos,
    const float* __restrict__ ipw, const float* __restrict__ opw,
    const float* __restrict__ l1w, const float* __restrict__ l2w,
    const float* __restrict__ fw1, const float* __restrict__ fw2,
    const float* __restrict__ clsw, const float* __restrict__ clsb,
    const float* __restrict__ fb2,
    float* __restrict__ emb, f16* __restrict__ embh,
    f16* __restrict__ wqkvh, f16* __restrict__ wq1h, f16* __restrict__ kvwh,
    f16* __restrict__ woh, f16* __restrict__ woh1,
    f16* __restrict__ l1wh, f16* __restrict__ l1wh1,
    f16* __restrict__ l2wh, f16* __restrict__ l2wh1,
    f16* __restrict__ w1ph, f16* __restrict__ w1ch, f16* __restrict__ fw2th,
    f16* __restrict__ cwgh, float* __restrict__ sv, float* __restrict__ ctx,
    int* __restrict__ map1, int* __restrict__ map2)
{
    int i = blockIdx.x * 256 + threadIdx.x;
    if (i < 327680) {                       // embed
        int r = i >> 8, j = i & 255;
        int p = r % TS;
        float v = etab[(size_t)tokens[r] * DM + j] + pos[p * DM + j];
        emb[i] = v; embh[i] = (f16)v;
        return;
    }
    i -= 327680;
    if (i < 196608) { wqkvh[i] = (f16)ipw[i]; return; }
    i -= 196608;
    if (i < 65536)  { wq1h[i] = (f16)ipw[196608 + i]; return; }
    i -= 65536;
    if (i < 131072) { kvwh[i] = (f16)ipw[262144 + i]; return; }
    i -= 131072;
    if (i < 65536)  { woh[i]  = (f16)opw[i]; return; }
    i -= 65536;
    if (i < 65536)  { woh1[i] = (f16)opw[65536 + i]; return; }
    i -= 65536;
    if (i < 262144) { l1wh[i]  = (f16)l1w[i]; return; }
    i -= 262144;
    if (i < 262144) { l1wh1[i] = (f16)l1w[262144 + i]; return; }
    i -= 262144;
    if (i < 262144) { l2wh[i]  = (f16)l2w[i]; return; }
    i -= 262144;
    if (i < 262144) { l2wh1[i] = (f16)l2w[262144 + i]; return; }
    i -= 262144;
    if (i < 98304) {                        // w1p (strided gather)
        int r = i / 384, c = i - r * 384;
        w1ph[i] = (f16)fw1[r * 640 + c];
        return;
    }
    i -= 98304;
    if (i < 65536) {                        // w1c (strided gather)
        int n = i >> 8, k = i & 255;
        w1ch[i] = (f16)fw1[n * 640 + 384 + k];
        return;
    }
    i -= 65536;
    if (i < 65536) {                        // fw2 transpose: fw2t[j,k]=fw2[k,j]
        int j = i >> 8, k = i & 255;
        fw2th[i] = (f16)fw2[k * 256 + j];
        return;
    }
    i -= 65536;
    if (i < 327680) {                       // cls gather: cwgh[tb,:] = cls_w[tok(t,b)]
        int tb = i >> 8, j = i & 255;
        int t = tb >> 5, b = tb & 31;
        cwgh[i] = (f16)clsw[(size_t)tokens[b * TS + t] * DM + j];
        return;
    }
    i -= 327680;
    if (i < 81920) {                        // s[tb] = fb2 . cls_w[tok] + clsb[tok]
        int tb = i >> 6, l = i & 63;
        int t = tb >> 5, b = tb & 31;
        int tok = tokens[b * TS + t];
        float a = 0.f;
#pragma unroll
        for (int c = 0; c < 4; ++c)
            a += fb2[l + 64 * c] * clsw[(size_t)tok * DM + l + 64 * c];
#pragma unroll
        for (int o = 32; o; o >>= 1) a += __shfl_xor(a, o);
        if (l == 0) sv[tb] = a + clsb[tok];
        return;
    }
    i -= 81920;
    if (i < 8192) { ctx[i] = 0.f; return; } // ctx rows t=0 (dedicated region)
    i -= 8192;
    if (i < NQ2) {
        int t = i >> 5, b = i & 31;
        map2[i] = ((t * (t + 1)) / 2 + t) * 32 + b;
    }
    if (i < NTOK) {
        int q = i >> 5, b = i & 31;
        int t = 0;
        while (((t + 1) * (t + 2)) / 2 <= q) ++t;
        int p = q - (t * (t + 1)) / 2;
        map1[i] = b * TS + p;
    }
}

// ---------------------------------------------------------------------------
// async 16B/lane global->LDS stage (wave-uniform LDS base) [m97/m104]
// ---------------------------------------------------------------------------
__device__ __forceinline__ void stage16(const f16* g, f16* lbase_wave_uniform) {
    __builtin_amdgcn_global_load_lds(
        (const __attribute__((address_space(1))) void*)g,
        (__attribute__((address_space(3))) void*)lbase_wave_uniform, 16, 0, 0);
}

__device__ __forceinline__ half8 load_frag8(const float* p) {
    float4 a0 = *(const float4*)p;
    float4 a1 = *(const float4*)(p + 4);
    half8 h;
    h[0] = (f16)a0.x; h[1] = (f16)a0.y; h[2] = (f16)a0.z; h[3] = (f16)a0.w;
    h[4] = (f16)a1.x; h[5] = (f16)a1.y; h[6] = (f16)a1.z; h[7] = (f16)a1.w;
    return h;
}

// ---------------------------------------------------------------------------
// MFMA GEMM: BM x 128 tile, 4 waves, balanced frag mapping. NBUF-deep async
// pipeline with counted vmcnt gates. (R18: NTOK-row GEMMs at BM=128 —
// verified r6; barrier-stall amortization is the mechanism, see r6 notes.)
// ---------------------------------------------------------------------------
template <int BM, int NBUF, typename TA, bool RELU, bool OUTF16>
__global__ __launch_bounds__(256) void gemm_x(
    const TA* __restrict__ A, int lda,
    const f16* __restrict__ B, int ldb,
    const float* __restrict__ bias,
    void* __restrict__ Cv, int ldc, int K)
{
    constexpr int AF  = BM / 8;       // # A frags
    constexpr int TF  = AF + 16;      // total frags
    constexpr int MRE = BM / 32;      // acc rows per wave
    constexpr int LPW = TF / 4;       // global_load_lds issued per wave per tile
    constexpr int TFS = TF * 512;     // f16 elems per buffer
    constexpr bool ASYNC = __is_same(TA, f16);
    __shared__ __align__(16) f16 lds[(ASYNC ? NBUF : 1) * TFS];
    int tid = threadIdx.x;
    int w = tid >> 6, l = tid & 63;
    int m0 = blockIdx.y * BM, n0 = blockIdx.x << 7;
    int lrow = l & 15;
    int lk8  = (l >> 4) << 3;
    int wm = w >> 1, wn = w & 1;

    f32x4 acc[MRE][4] = {};

    auto stage = [&](f16* dst, int k0) {
#pragma unroll
        for (int j = 0; j < TF / 4; ++j) {
            int f = (j << 2) | w;                      // balanced across waves
            if (f < AF) {
                int mi = f >> 1, kc = f & 1;
                const TA* ga = A + (size_t)(m0 + (mi << 4) + lrow) * lda + k0 + (kc << 5) + lk8;
                if constexpr (ASYNC) {
                    stage16((const f16*)ga, dst + (f << 9));
                } else {
                    *(half8*)&dst[(f << 9) + (l << 3)] = load_frag8((const float*)ga);
                }
            } else {
                int fb = f - AF;
                int nj = fb >> 1, kc = fb & 1;
                const f16* gb = B + (size_t)(n0 + (nj << 4) + lrow) * ldb + k0 + (kc << 5) + lk8;
                stage16(gb, dst + (f << 9));
            }
        }
    };

    auto compute = [&](const f16* buf) {
#pragma unroll
        for (int kc = 0; kc < 2; ++kc) {
            half8 af[MRE], bfr[4];
#pragma unroll
            for (int i = 0; i < MRE; ++i)
                af[i] = *(const half8*)&buf[((((wm * MRE + i) << 1) | kc) << 9) + (l << 3)];
#pragma unroll
            for (int j2 = 0; j2 < 4; ++j2)
                bfr[j2] = *(const half8*)&buf[((AF + ((((wn << 2) | j2) << 1) | kc)) << 9) + (l << 3)];
#pragma unroll
            for (int i = 0; i < MRE; ++i)
#pragma unroll
                for (int j2 = 0; j2 < 4; ++j2)
                    acc[i][j2] = __builtin_amdgcn_mfma_f32_16x16x32_f16(
                        af[i], bfr[j2], acc[i][j2], 0, 0, 0);
        }
    };

    if constexpr (ASYNC) {
        int nk = K >> 6;
        // prologue: stage tiles 0..NBUF-2  (requires nk >= NBUF-1; K>=256 ok)
#pragma unroll
        for (int s = 0; s < NBUF - 1; ++s)
            stage(lds + s * TFS, s << 6);
        int cb = 0;                                    // buffer of tile t
        for (int t = 0; t < nk; ++t) {
            if constexpr (NBUF == 3) {
                if (t + 2 < nk) {
                    int sb = cb + 2; if (sb >= 3) sb -= 3;
                    stage(lds + sb * TFS, (t + 2) << 6);
                    asm volatile("s_waitcnt vmcnt(%0)" :: "i"(2 * LPW) : "memory");
                } else if (t + 1 < nk) {
                    asm volatile("s_waitcnt vmcnt(%0)" :: "i"(LPW) : "memory");
                } else {
                    asm volatile("s_waitcnt vmcnt(0)" ::: "memory");
                }
            } else {
                if (t + 1 < nk) {
                    stage(lds + (cb ^ 1) * TFS, (t + 1) << 6);
                    asm volatile("s_waitcnt vmcnt(%0)" :: "i"(LPW) : "memory");
                } else {
                    asm volatile("s_waitcnt vmcnt(0)" ::: "memory");
                }
            }
            __builtin_amdgcn_s_barrier();               // all waves' tile t in LDS
            asm volatile("" ::: "memory");
            compute(lds + cb * TFS);
            asm volatile("" ::: "memory");
            __builtin_amdgcn_s_barrier();               // tile-t buffer free
            asm volatile("" ::: "memory");
            cb = (cb + 1 == NBUF) ? 0 : cb + 1;
        }
    } else {
        for (int k0 = 0; k0 < K; k0 += 64) {
            stage(lds, k0);
            __syncthreads();
            compute(lds);
            __syncthreads();
        }
    }

    int colq = l & 15, rowq = (l >> 4) << 2;           // C/D map [m89/m91]
#pragma unroll
    for (int i = 0; i < MRE; ++i) {
        int gmb = m0 + (wm * MRE + i) * 16 + rowq;
#pragma unroll
        for (int j2 = 0; j2 < 4; ++j2) {
            int gn = n0 + ((wn << 2) | j2) * 16 + colq;
            float bv = bias ? bias[gn] : 0.f;
#pragma unroll
            for (int r = 0; r < 4; ++r) {
                float v = acc[i][j2][r] + bv;
                if (RELU) v = fmaxf(v, 0.f);
                if (OUTF16)
                    ((f16*)Cv)[(size_t)(gmb + r) * ldc + gn] = (f16)v;
                else
                    ((float*)Cv)[(size_t)(gmb + r) * ldc + gn] = v;
            }
        }
    }
}

// ---------------------------------------------------------------------------
// LayerNorm (ROUND-17): templated on input/residual precision. One WAVE per
// row, stats always computed in f32. Writes f16 (outh) and/or f32 (outf).
// ---------------------------------------------------------------------------
template <bool XF16, bool RESF16>
__global__ __launch_bounds__(256) void ln_k(
    const void* __restrict__ Xv, const void* __restrict__ resv,
    const int* __restrict__ map, const float* __restrict__ g,
    const float* __restrict__ beta, int nrows,
    f16* __restrict__ outh, float* __restrict__ outf)
{
    int r = blockIdx.x * 4 + (threadIdx.x >> 6);
    if (r >= nrows) return;
    int l = threadIdx.x & 63;
    float4 v;
    if constexpr (XF16) {
        half4 xh = *(const half4*)((const f16*)Xv + (size_t)r * DM + l * 4);
        v.x = (float)xh[0]; v.y = (float)xh[1]; v.z = (float)xh[2]; v.w = (float)xh[3];
    } else {
        v = *(const float4*)((const float*)Xv + (size_t)r * DM + l * 4);
    }
    {
        int rr = map ? map[r] : r;
        if constexpr (RESF16) {
            half4 rh = *(const half4*)((const f16*)resv + (size_t)rr * DM + l * 4);
            v.x += (float)rh[0]; v.y += (float)rh[1];
            v.z += (float)rh[2]; v.w += (float)rh[3];
        } else {
            float4 rv = *(const float4*)((const float*)resv + (size_t)rr * DM + l * 4);
            v.x += rv.x; v.y += rv.y; v.z += rv.z; v.w += rv.w;
        }
    }
    float s = v.x + v.y + v.z + v.w;
#pragma unroll
    for (int o = 32; o; o >>= 1) s += __shfl_xor(s, o);
    float mean = s * (1.f / 256.f);
    float dx = v.x - mean, dy = v.y - mean, dz = v.z - mean, dw = v.w - mean;
    float s2 = dx * dx + dy * dy + dz * dz + dw * dw;
#pragma unroll
    for (int o = 32; o; o >>= 1) s2 += __shfl_xor(s2, o);
    float rstd = 1.f / sqrtf(s2 * (1.f / 256.f) + 1e-5f);
    float4 gv = *(const float4*)(g + l * 4);
    float4 bv = *(const float4*)(beta + l * 4);
    float4 ov;
    ov.x = dx * rstd * gv.x + bv.x;
    ov.y = dy * rstd * gv.y + bv.y;
    ov.z = dz * rstd * gv.z + bv.z;
    ov.w = dw * rstd * gv.w + bv.w;
    if (outf) *(float4*)(outf + (size_t)r * DM + l * 4) = ov;
    if (outh) {
        half4 oh;
        oh[0] = (f16)ov.x; oh[1] = (f16)ov.y; oh[2] = (f16)ov.z; oh[3] = (f16)ov.w;
        *(half4*)(outh + (size_t)r * DM + l * 4) = oh;
    }
}

// ---------------------------------------------------------------------------
// Layer-0 attention, online-softmax prefix scan (f16 qkv, f16 packed out).
// ---------------------------------------------------------------------------
__global__ __launch_bounds__(256) void attn0_kernel(
    const f16* __restrict__ qkv, f16* __restrict__ ao)
{
    int bp = blockIdx.x;               // b*39 + p
    int b = bp / 39, p = bp % 39;
    int tid = threadIdx.x;
    int h = tid >> 6, l = tid & 63;

    float qv = (float)qkv[(size_t)(b * TS + p) * 768 + h * 64 + l];

    int krow = (l < 39) ? l : 38;
    const f16* Kr = qkv + (size_t)(b * TS + krow) * 768 + 256 + h * 64;
    float acc = 0.f;
#pragma unroll
    for (int c = 0; c < 8; ++c) {
        half8 k8 = *(const half8*)(Kr + c * 8);
#pragma unroll
        for (int j = 0; j < 8; ++j)
            acc += __shfl(qv, c * 8 + j) * (float)k8[j];
    }
    float s = acc * 0.125f;

    float m = -1e30f, lsum = 0.f, o = 0.f;
    for (int t = p; t < TM1; ++t) {
        float st = __shfl(s, t);
        float mnew = fmaxf(m, st);
        float c = __expf(m - mnew);
        float e = __expf(st - mnew);
        lsum = lsum * c + e;
        float vv = (float)qkv[(size_t)(b * TS + t) * 768 + 512 + h * 64 + l];
        o = o * c + e * vv;
        m = mnew;
        int row = ((t * (t + 1)) >> 1) + p;
        ao[((size_t)row * 32 + b) * DM + h * 64 + l] = (f16)(o / lsum);
    }
}

// ---------------------------------------------------------------------------
// Layer-1 attention. Block per (t,b): 4 waves = 4 heads. h1 row from h1h f16.
// ---------------------------------------------------------------------------
__global__ __launch_bounds__(256) void attn1_kernel(
    const f16* __restrict__ h1h, const f16* __restrict__ kv1,
    const f16* __restrict__ Wq, const float* __restrict__ bq,
    f16* __restrict__ ao1)
{
    int tb = blockIdx.x;
    int t = tb >> 5, b = tb & 31;
    int tid = threadIdx.x;
    int h = tid >> 6, l = tid & 63;
    int tri = (t * (t + 1)) >> 1;
    __shared__ float h1r[DM];
    h1r[tid] = (float)h1h[((size_t)(tri + t) * 32 + b) * DM + tid];
    __syncthreads();

    float q = bq[h * 64 + l];
    const half8* w8 = (const half8*)(Wq + (size_t)(h * 64 + l) * DM);
#pragma unroll 8
    for (int c = 0; c < 32; ++c) {
        half8 ww = w8[c];
#pragma unroll
        for (int j = 0; j < 8; ++j)
            q += (float)ww[j] * h1r[c * 8 + j];
    }

    int kr = (l <= t) ? l : t;
    const f16* Kp = kv1 + ((size_t)(tri + kr) * 32 + b) * 512 + h * 64;
    float sc = 0.f;
#pragma unroll
    for (int c = 0; c < 8; ++c) {
        half8 k8 = *(const half8*)(Kp + c * 8);
#pragma unroll
        for (int j = 0; j < 8; ++j)
            sc += __shfl(q, c * 8 + j) * (float)k8[j];
    }
    sc = (l <= t) ? sc * 0.125f : -1e30f;
    float m = sc;
#pragma unroll
    for (int o = 32; o; o >>= 1) m = fmaxf(m, __shfl_xor(m, o));
    float e = (l <= t) ? __expf(sc - m) : 0.f;
    float ss = e;
#pragma unroll
    for (int o = 32; o; o >>= 1) ss += __shfl_xor(ss, o);
    float a = e / ss;

    float o = 0.f;
    for (int k = 0; k <= t; ++k) {
        float ak = __shfl(a, k);
        o += ak * (float)kv1[((size_t)(tri + k) * 32 + b) * 512 + 256 + h * 64 + l];
    }
    ao1[(size_t)tb * DM + h * 64 + l] = (f16)o;
}

// ---------------------------------------------------------------------------
// Fast gelu via A&S 7.1.25 erf (|err| <= 5e-4, no exp).
// ---------------------------------------------------------------------------
__device__ __forceinline__ float gelu_f(float x)
{
    float ax = fabsf(x);
    float z  = ax * 0.70710678118654752440f;
    float d  = 1.f + z * (0.278393f + z * (0.230389f + z * (0.000972f + z * 0.078108f)));
    float d2 = d * d;
    float E  = 1.f - __builtin_amdgcn_rcpf(d2 * d2);
    return 0.5f * x + 0.5f * ax * E;
}

// ---------------------------------------------------------------------------
// out[b,p,t] = sigmoid( sum_k gelu(pp+cpb)*u + s )
//
// ROUND-19: 8-wave (512-thread) variant. R18 counters: VALUBusy 57.7%,
// Occ 17.8%, HBM 5.8% — VALU-floor-bound (~84M gelu terms ~= 19-28 us of
// VALU) but under-occupied: 640x4 waves ~= 2.5 waves/SIMD can't hide the
// uniform cpb/u L2 loads between FMA chains. 8 waves/block (one t per wave,
// 2 acc chains from the float2 halves) doubles resident waves at the SAME
// LDS (32 KB) and FETCH (pp re-read factor unchanged at 5x).
// ---------------------------------------------------------------------------
__global__ __launch_bounds__(512) void final_out(
    const f16* __restrict__ pp, const float* __restrict__ cpb,
    const float* __restrict__ u, const float* __restrict__ sv,
    float* __restrict__ out)
{
    // blockIdx.x = b*20 + pg*5 + tg   (32 * 4 * 5 = 640 blocks)
    int blk = blockIdx.x;
    int b  = blk / 20;
    int rr = blk - b * 20;
    int pg = rr / 5;
    int tg = rr - pg * 5;
    int tid = threadIdx.x;
    int w = tid >> 6, l = tid & 63;    // 8 waves

    __shared__ unsigned ldsT[128 * 64];   // [k2][p] packed f16x2 = 32 KB

    {   // stage-transpose 64p x 256k pp tile: lane = p row, wave = 32-k slice.
        const f16* rowp = pp + (size_t)((b << 8) + (pg << 6) + l) * DM + (w << 5);
#pragma unroll
        for (int j = 0; j < 4; ++j) {
            half8 h8 = *(const half8*)(rowp + j * 8);
#pragma unroll
            for (int j2 = 0; j2 < 4; ++j2) {
                union { f16 h[2]; unsigned v; } cv;
                cv.h[0] = h8[j2 * 2]; cv.h[1] = h8[j2 * 2 + 1];
                int k2 = (w << 4) + (j << 2) + j2;
                ldsT[(k2 << 6) + l] = cv.v;
            }
        }
    }
    __syncthreads();

    int t0  = tg * 8 + w;                              // wave's single t
    int tb0 = __builtin_amdgcn_readfirstlane(t0 * 32 + b);
    const float* cpa = cpb + (size_t)tb0 * DM;
    const float* ua  = u + (size_t)tb0 * DM;

    float accx = 0.f, accy = 0.f;                      // 2 independent chains
#pragma unroll 8
    for (int k2 = 0; k2 < 128; ++k2) {
        union { unsigned v; f16 h[2]; } pr;
        pr.v = ldsT[(k2 << 6) + l];
        float a0 = (float)pr.h[0], a1 = (float)pr.h[1];
        float2 c0 = *(const float2*)(cpa + (k2 << 1));
        float2 u0 = *(const float2*)(ua + (k2 << 1));
        accx += gelu_f(a0 + c0.x) * u0.x;
        accy += gelu_f(a1 + c0.y) * u0.y;
    }
    float s0 = sv[tb0];
    int op = ((b << 8) + (pg << 6) + l) * TS;
    out[op + t0] = 1.f / (1.f + __expf(-(accx + accy + s0)));
}

// ---------------------------------------------------------------------------
// Launcher
// ---------------------------------------------------------------------------
extern "C" void kernel_launch(void* const* d_in, const int* in_sizes, int n_in,
                              void* d_out, int out_size, void* d_ws, size_t ws_size,
                              hipStream_t stream)
{
    (void)in_sizes; (void)n_in; (void)out_size;
    const float* patches   = (const float*)d_in[0];
    const int*   tokens    = (const int*)  d_in[1];
    const float* embedding = (const float*)d_in[2];
    const float* pos_emb   = (const float*)d_in[3];
    const float* in_proj_w = (const float*)d_in[4];
    const float* in_proj_b = (const float*)d_in[5];
    const float* out_proj_w= (const float*)d_in[6];
    const float* out_proj_b= (const float*)d_in[7];
    const float* lin1_w    = (const float*)d_in[8];
    const float* lin1_b    = (const float*)d_in[9];
    const float* lin2_w    = (const float*)d_in[10];
    const float* lin2_b    = (const float*)d_in[11];
    const float* ln1_g     = (const float*)d_in[12];
    const float* ln1_b     = (const float*)d_in[13];
    const float* ln2_g     = (const float*)d_in[14];
    const float* ln2_b     = (const float*)d_in[15];
    const float* fus_w1    = (const float*)d_in[16];
    const float* fus_b1    = (const float*)d_in[17];
    const float* fus_w2    = (const float*)d_in[18];
    const float* fus_b2    = (const float*)d_in[19];
    const float* cls_w     = (const float*)d_in[20];
    const float* cls_b     = (const float*)d_in[21];

    if (ws_size < (size_t)WS_FLOATS * 4) return;

    float* ws   = (float*)d_ws;
    f16*   embh = (f16*)(ws + OFF_EMBH);
    float* emb  = ws + OFF_EMB;           // dead (kept for layout stability)
    f16*   qkvh = (f16*)(ws + OFF_QKVH);
    f16*   x1p  = (f16*)(ws + OFF_X1);    // pre-LN attn-block out (f16)
    f16*   x1h  = (f16*)(ws + OFF_X1H);   // ln1 out (f16)
    f16*   pph  = (f16*)(ws + OFF_X1H);   // aliases x1h head (x1h dead after ln2)
    f16*   h1p  = (f16*)(ws + OFF_H1);    // pre-LN ffn out (f16)
    float* big  = ws + OFF_BIG;
    f16*   ao0h = (f16*)big;              // head; dead after out-proj0
    f16*   ff1h = (f16*)big;              // spans ALL of big; dead after lin2
    f16*   kv1h = (f16*)big;              // head; dead after attn1
    f16*   ao1h = (f16*)(big + BT_AO1H);
    float* x2   = big + BT_X2;
    f16*   x2h  = (f16*)(big + BT_X2H);
    f16*   ff2h = (f16*)(big + BT_FF2H);
    f16*   h1h  = (f16*)(big + BT_H1H);   // ln2 out (f16): kv/attn1/ln-x2 res
    float* ctx  = ws + OFF_CTX;           // dedicated; rows 0..31 zeroed by prep
    float* cpb  = ws + OFF_CPB;
    float* u    = ws + OFF_U;
    float* svec = ws + OFF_S;
    f16*   wqkvh= (f16*)(ws + OFF_WQKVH);
    f16*   wq1h = (f16*)(ws + OFF_WQ1H);
    f16*   kvwh = (f16*)(ws + OFF_KVWH);
    f16*   woh  = (f16*)(ws + OFF_WOH);
    f16*   woh1 = (f16*)(ws + OFF_WOH1);
    f16*   l1wh = (f16*)(ws + OFF_L1WH);
    f16*   l1wh1= (f16*)(ws + OFF_L1WH1);
    f16*   l2wh = (f16*)(ws + OFF_L2WH);
    f16*   l2wh1= (f16*)(ws + OFF_L2WH1);
    f16*   w1ph = (f16*)(ws + OFF_W1PH);
    f16*   w1ch = (f16*)(ws + OFF_W1CH);
    f16*   fw2th= (f16*)(ws + OFF_FW2TH);
    f16*   cwgh = (f16*)(ws + OFF_CWGH);
    int*   map1 = (int*)(ws + OFF_MAP);
    int*   map2 = map1 + NTOK;

    prep_kernel<<<10050, 256, 0, stream>>>(
        tokens, embedding, pos_emb, in_proj_w, out_proj_w, lin1_w, lin2_w,
        fus_w1, fus_w2, cls_w, cls_b, fus_b2,
        emb, embh, wqkvh, wq1h, kvwh, woh, woh1, l1wh, l1wh1, l2wh, l2wh1,
        w1ph, w1ch, fw2th, cwgh, svec, ctx, map1, map2);

    // u = cwg @ fw2t^T : M=1280(20x64), N=256(2), K=256 (u dedicated — safe early)
    gemm_x<64, 3, f16, false, false><<<dim3(2, 20), 256, 0, stream>>>(
        cwgh, DM, fw2th, DM, nullptr, u, DM, DM);

    // ---- Layer 0 ----
    gemm_x<64, 3, f16, false, true><<<dim3(6, 20), 256, 0, stream>>>(
        embh, DM, wqkvh, DM, in_proj_b, qkvh, 768, DM);
    attn0_kernel<<<NQ2, 256, 0, stream>>>(qkvh, ao0h);
    // out-proj0 -> x1p (f16 pre-LN); BM=128 (r6)
    gemm_x<128, 2, f16, false, true><<<dim3(2, 195), 256, 0, stream>>>(
        ao0h, DM, woh, DM, out_proj_b, x1p, DM, DM);
    // ln1: x1h = LN(x1p + embh[map1])
    ln_k<true, true><<<6240, 256, 0, stream>>>(
        x1p, embh, map1, ln1_g, ln1_b, NTOK, x1h, nullptr);
    gemm_x<128, 2, f16, true, true><<<dim3(8, 195), 256, 0, stream>>>(
        x1h, DM, l1wh, DM, lin1_b, ff1h, DFF, DM);
    // lin2 -> h1p (f16 pre-LN); BM=128 (r6)
    gemm_x<128, 2, f16, false, true><<<dim3(2, 195), 256, 0, stream>>>(
        ff1h, DFF, l2wh, DFF, lin2_b, h1p, DM, DFF);
    // ln2: h1h = LN(h1p + x1h)   (h1h in big tail; ff1h dead now)
    ln_k<true, true><<<6240, 256, 0, stream>>>(
        h1p, x1h, nullptr, ln2_g, ln2_b, NTOK, h1h, nullptr);

    // pp: M=8192(128x64), N=256(2), K=384 (x1h head free AFTER ln2 -> pph)
    gemm_x<64, 1, float, false, true><<<dim3(2, 128), 256, 0, stream>>>(
        patches, DINO, w1ph, DINO, nullptr, pph, DM, DINO);

    // ---- Layer 1 ----
    // K/V: A = h1h f16 async, N=512(4) -> kv1h (big head; disjoint from h1h tail)
    gemm_x<128, 2, f16, false, true><<<dim3(4, 195), 256, 0, stream>>>(
        h1h, DM, kvwh, DM, in_proj_b + 768 + 256, kv1h, 512, DM);
    attn1_kernel<<<NQ2, 256, 0, stream>>>(
        h1h, kv1h, wq1h, in_proj_b + 768, ao1h);
    // out-proj1 (MFMA, M padded to 1280; pad rows garbage, never read)
    gemm_x<64, 3, f16, false, false><<<dim3(2, 20), 256, 0, stream>>>(
        ao1h, DM, woh1, DM, out_proj_b + DM, x2, DM, DM);
    // ln(x2): res = h1h[map2] (f16); writes x2 (f32, residual for ln-ctx) + x2h
    ln_k<false, true><<<312, 256, 0, stream>>>(
        x2, h1h, map2, ln1_g + DM, ln1_b + DM, NQ2, x2h, x2);
    gemm_x<64, 3, f16, true, true><<<dim3(8, 20), 256, 0, stream>>>(
        x2h, DM, l1wh1, DM, lin1_b + DFF, ff2h, DFF, DM);
    // pad rows spill 8192 floats into cpb head; cpb-gemm rewrites cpb below
    gemm_x<64, 3, f16, false, false><<<dim3(2, 20), 256, 0, stream>>>(
        ff2h, DFF, l2wh1, DFF, lin2_b + DM, ctx + BB * DM, DM, DFF);
    // ln(ctx): res = x2 (f32); f32 in-place (cpb-gemm reads ctx as float)
    ln_k<false, false><<<312, 256, 0, stream>>>(
        ctx + BB * DM, x2, nullptr, ln2_g + DM, ln2_b + DM, NQ2, nullptr,
        ctx + BB * DM);

    // cpb = ctx @ w1c^T + fus_b1 : M=1280(20x64), N=256(2), K=256
    gemm_x<64, 1, float, false, false><<<dim3(2, 20), 256, 0, stream>>>(
        ctx, DM, w1ch, DM, fus_b1, cpb, DM, DM);

    final_out<<<640, 512, 0, stream>>>(pph, cpb, u, svec, (float*)d_out);
}

// Round 9
// 412.546 us; speedup vs baseline: 1.0172x; 1.0172x over previous
//
#include <hip/hip_runtime.h>
#include <math.h>

// ---------------------------------------------------------------------------
// Problem constants
// ---------------------------------------------------------------------------
#define DM    256     // D_MODEL
#define NH    4
#define HD    64
#define TS    40
#define TM1   39
#define BB    32
#define DFF   1024
#define DINO  384
#define NPATCH 256
#define VOCAB 4096

#define NTOK  24960   // 780*32 packed (t, p<=t, b) tokens
#define NQ2   1248    // 39*32

typedef _Float16 f16;
typedef __attribute__((ext_vector_type(8))) _Float16 half8;  // MFMA A/B frag
typedef __attribute__((ext_vector_type(4))) _Float16 half4;
typedef __attribute__((ext_vector_type(4))) float f32x4;

// ---------------------------------------------------------------------------
// Workspace layout (float offsets), 127.25 MB total (< 127.57 proven budget).
// ROUND-17: f16 activation chain (x1p/x1h/h1p/h1h) — verified r5.
// ROUND-18: out-proj0 & lin2 -> BM=128 — verified r6 (left top-5).
// ROUND-19: final_out 8-wave restructure — improved (left top-5 r8).
// ROUND-20: bijective XCD-chunked block swizzle in gemm_x (see comment).
// ---------------------------------------------------------------------------
#define OFF_EMBH   0u          /* f16 1280*256  = 327680 h -> 163840 fl */
#define OFF_EMB    163840u     /* f32 1280*256  -> 327680 fl (dead; kept) */
#define OFF_QKVH   491520u     /* f16 1280*768  = 983040 h -> 491520 fl */
#define OFF_X1     983040u     /* x1p: f16 24960*256 (pre-LN attn-block out) */
#define OFF_X1H    7372800u    /* f16 24960*256 (ln1 out); pph aliases head */
#define OFF_H1     10567680u   /* h1p: f16 24960*256 (pre-LN ffn out) */
#define OFF_BIG    16957440u   /* 12779520 fl */
/* big interior (float offsets from big):
     head [0,6389760)         : ao0h (attn0..outproj0) / ff1h spans ALL of big
                                (lin1..lin2) / kv1h (kv..attn1)
     BT_AO1H  [6389760,6553600)   f16 1280*256, written by attn1
     BT_X2    [6553600,6881280)   f32 1280*256, written by out-proj1
     BT_X2H   [6881280,7045120)   f16 1280*256, written by ln(x2)
     BT_FF2H  [7045120,7700480)   f16 1280*1024, written by lin1-l1
     BT_H1H   [7700480,10895360)  f16 24960*256, written by ln2 (post-lin2),
                                  read by kv-gemm/attn1/ln-x2 residual. */
#define   BT_AO1H  6389760u
#define   BT_X2    6553600u
#define   BT_X2H   6881280u
#define   BT_FF2H  7045120u
#define   BT_H1H   7700480u
#define OFF_CTX    29736960u   /* f32 1280*256 -> 327680 fl (rows 0..31 zeroed by prep) */
#define OFF_CPB    30064640u   /* f32 1280*256 (lin2-l1 pad spill lands here; rewritten) */
#define OFF_U      30392320u   /* f32 1280*256 (dedicated) */
#define OFF_S      30720000u   /* f32 2048 fl */
#define OFF_WQKVH  30722048u   /* f16 768*256 */
#define OFF_WQ1H   30820352u   /* f16 256*256 */
#define OFF_KVWH   30853120u   /* f16 512*256 */
#define OFF_WOH    30918656u   /* f16 256*256 */
#define OFF_WOH1   30951424u   /* f16 256*256 */
#define OFF_L1WH   30984192u   /* f16 1024*256 */
#define OFF_L1WH1  31115264u   /* f16 1024*256 */
#define OFF_L2WH   31246336u   /* f16 256*1024 */
#define OFF_L2WH1  31377408u   /* f16 256*1024 */
#define OFF_W1PH   31508480u   /* f16 256*384 */
#define OFF_W1CH   31557632u   /* f16 256*256 */
#define OFF_FW2TH  31590400u   /* f16 256*256 */
#define OFF_CWGH   31623168u   /* f16 1280*256 */
#define OFF_MAP    31787008u   /* int 24960+1248 */
#define WS_FLOATS  31813216u   /* = 127.25 MB < 127.57 known-good */

// ---------------------------------------------------------------------------
// prep: embed | all weight f16 conversions | w1p/w1c/fw2t gathers | cls
// gather | s vector | ctx t=0 zeros | maps.
// ---------------------------------------------------------------------------
__global__ __launch_bounds__(256) void prep_kernel(
    const int* __restrict__ tokens, const float* __restrict__ etab,
    const float* __restrict__ pos,
    const float* __restrict__ ipw, const float* __restrict__ opw,
    const float* __restrict__ l1w, const float* __restrict__ l2w,
    const float* __restrict__ fw1, const float* __restrict__ fw2,
    const float* __restrict__ clsw, const float* __restrict__ clsb,
    const float* __restrict__ fb2,
    float* __restrict__ emb, f16* __restrict__ embh,
    f16* __restrict__ wqkvh, f16* __restrict__ wq1h, f16* __restrict__ kvwh,
    f16* __restrict__ woh, f16* __restrict__ woh1,
    f16* __restrict__ l1wh, f16* __restrict__ l1wh1,
    f16* __restrict__ l2wh, f16* __restrict__ l2wh1,
    f16* __restrict__ w1ph, f16* __restrict__ w1ch, f16* __restrict__ fw2th,
    f16* __restrict__ cwgh, float* __restrict__ sv, float* __restrict__ ctx,
    int* __restrict__ map1, int* __restrict__ map2)
{
    int i = blockIdx.x * 256 + threadIdx.x;
    if (i < 327680) {                       // embed
        int r = i >> 8, j = i & 255;
        int p = r % TS;
        float v = etab[(size_t)tokens[r] * DM + j] + pos[p * DM + j];
        emb[i] = v; embh[i] = (f16)v;
        return;
    }
    i -= 327680;
    if (i < 196608) { wqkvh[i] = (f16)ipw[i]; return; }
    i -= 196608;
    if (i < 65536)  { wq1h[i] = (f16)ipw[196608 + i]; return; }
    i -= 65536;
    if (i < 131072) { kvwh[i] = (f16)ipw[262144 + i]; return; }
    i -= 131072;
    if (i < 65536)  { woh[i]  = (f16)opw[i]; return; }
    i -= 65536;
    if (i < 65536)  { woh1[i] = (f16)opw[65536 + i]; return; }
    i -= 65536;
    if (i < 262144) { l1wh[i]  = (f16)l1w[i]; return; }
    i -= 262144;
    if (i < 262144) { l1wh1[i] = (f16)l1w[262144 + i]; return; }
    i -= 262144;
    if (i < 262144) { l2wh[i]  = (f16)l2w[i]; return; }
    i -= 262144;
    if (i < 262144) { l2wh1[i] = (f16)l2w[262144 + i]; return; }
    i -= 262144;
    if (i < 98304) {                        // w1p (strided gather)
        int r = i / 384, c = i - r * 384;
        w1ph[i] = (f16)fw1[r * 640 + c];
        return;
    }
    i -= 98304;
    if (i < 65536) {                        // w1c (strided gather)
        int n = i >> 8, k = i & 255;
        w1ch[i] = (f16)fw1[n * 640 + 384 + k];
        return;
    }
    i -= 65536;
    if (i < 65536) {                        // fw2 transpose: fw2t[j,k]=fw2[k,j]
        int j = i >> 8, k = i & 255;
        fw2th[i] = (f16)fw2[k * 256 + j];
        return;
    }
    i -= 65536;
    if (i < 327680) {                       // cls gather: cwgh[tb,:] = cls_w[tok(t,b)]
        int tb = i >> 8, j = i & 255;
        int t = tb >> 5, b = tb & 31;
        cwgh[i] = (f16)clsw[(size_t)tokens[b * TS + t] * DM + j];
        return;
    }
    i -= 327680;
    if (i < 81920) {                        // s[tb] = fb2 . cls_w[tok] + clsb[tok]
        int tb = i >> 6, l = i & 63;
        int t = tb >> 5, b = tb & 31;
        int tok = tokens[b * TS + t];
        float a = 0.f;
#pragma unroll
        for (int c = 0; c < 4; ++c)
            a += fb2[l + 64 * c] * clsw[(size_t)tok * DM + l + 64 * c];
#pragma unroll
        for (int o = 32; o; o >>= 1) a += __shfl_xor(a, o);
        if (l == 0) sv[tb] = a + clsb[tok];
        return;
    }
    i -= 81920;
    if (i < 8192) { ctx[i] = 0.f; return; } // ctx rows t=0 (dedicated region)
    i -= 8192;
    if (i < NQ2) {
        int t = i >> 5, b = i & 31;
        map2[i] = ((t * (t + 1)) / 2 + t) * 32 + b;
    }
    if (i < NTOK) {
        int q = i >> 5, b = i & 31;
        int t = 0;
        while (((t + 1) * (t + 2)) / 2 <= q) ++t;
        int p = q - (t * (t + 1)) / 2;
        map1[i] = b * TS + p;
    }
}

// ---------------------------------------------------------------------------
// async 16B/lane global->LDS stage (wave-uniform LDS base) [m97/m104]
// ---------------------------------------------------------------------------
__device__ __forceinline__ void stage16(const f16* g, f16* lbase_wave_uniform) {
    __builtin_amdgcn_global_load_lds(
        (const __attribute__((address_space(1))) void*)g,
        (__attribute__((address_space(3))) void*)lbase_wave_uniform, 16, 0, 0);
}

__device__ __forceinline__ half8 load_frag8(const float* p) {
    float4 a0 = *(const float4*)p;
    float4 a1 = *(const float4*)(p + 4);
    half8 h;
    h[0] = (f16)a0.x; h[1] = (f16)a0.y; h[2] = (f16)a0.z; h[3] = (f16)a0.w;
    h[4] = (f16)a1.x; h[5] = (f16)a1.y; h[6] = (f16)a1.z; h[7] = (f16)a1.w;
    return h;
}

// ---------------------------------------------------------------------------
// MFMA GEMM: BM x 128 tile, 4 waves, balanced frag mapping. NBUF-deep async
// pipeline with counted vmcnt gates. (R18: NTOK-row GEMMs at BM=128.)
//
// ROUND-20: bijective XCD-chunked swizzle (T1/m204). R8 counters: lin1
// FETCH 50.5 MB vs A=12.8 MB — the 8 N-blocks sharing an A row-tile
// round-robin onto 8 different XCD L2s, so each tile is HBM-fetched ~4-8x,
// AND (the real cost, per R5's traffic-neutral lesson) the stage loads pay
// HBM latency (~900cy) instead of L2 (~250cy) inside the vmcnt gate stall.
// Remap linear block id d (XCD = d%8 dispatch heuristic) so each XCD owns a
// CONTIGUOUS tile range in n-fastest order: same-A-row blocks share one L2.
// Pure index bijection — no sync-structure change.
// ---------------------------------------------------------------------------
template <int BM, int NBUF, typename TA, bool RELU, bool OUTF16>
__global__ __launch_bounds__(256) void gemm_x(
    const TA* __restrict__ A, int lda,
    const f16* __restrict__ B, int ldb,
    const float* __restrict__ bias,
    void* __restrict__ Cv, int ldc, int K)
{
    constexpr int AF  = BM / 8;       // # A frags
    constexpr int TF  = AF + 16;      // total frags
    constexpr int MRE = BM / 32;      // acc rows per wave
    constexpr int LPW = TF / 4;       // global_load_lds issued per wave per tile
    constexpr int TFS = TF * 512;     // f16 elems per buffer
    constexpr bool ASYNC = __is_same(TA, f16);
    __shared__ __align__(16) f16 lds[(ASYNC ? NBUF : 1) * TFS];
    int tid = threadIdx.x;
    int w = tid >> 6, l = tid & 63;

    // ---- XCD-chunked bijective swizzle (m204) ----
    int gx  = gridDim.x;
    int nwg = gx * gridDim.y;
    int d   = blockIdx.y * gx + blockIdx.x;
    int q8  = nwg >> 3, r8 = nwg & 7;
    int c8  = d & 7, j8 = d >> 3;
    int lid = (c8 < r8 ? c8 * (q8 + 1) : r8 * (q8 + 1) + (c8 - r8) * q8) + j8;
    int m0 = (lid / gx) * BM, n0 = (lid % gx) << 7;

    int lrow = l & 15;
    int lk8  = (l >> 4) << 3;
    int wm = w >> 1, wn = w & 1;

    f32x4 acc[MRE][4] = {};

    auto stage = [&](f16* dst, int k0) {
#pragma unroll
        for (int j = 0; j < TF / 4; ++j) {
            int f = (j << 2) | w;                      // balanced across waves
            if (f < AF) {
                int mi = f >> 1, kc = f & 1;
                const TA* ga = A + (size_t)(m0 + (mi << 4) + lrow) * lda + k0 + (kc << 5) + lk8;
                if constexpr (ASYNC) {
                    stage16((const f16*)ga, dst + (f << 9));
                } else {
                    *(half8*)&dst[(f << 9) + (l << 3)] = load_frag8((const float*)ga);
                }
            } else {
                int fb = f - AF;
                int nj = fb >> 1, kc = fb & 1;
                const f16* gb = B + (size_t)(n0 + (nj << 4) + lrow) * ldb + k0 + (kc << 5) + lk8;
                stage16(gb, dst + (f << 9));
            }
        }
    };

    auto compute = [&](const f16* buf) {
#pragma unroll
        for (int kc = 0; kc < 2; ++kc) {
            half8 af[MRE], bfr[4];
#pragma unroll
            for (int i = 0; i < MRE; ++i)
                af[i] = *(const half8*)&buf[((((wm * MRE + i) << 1) | kc) << 9) + (l << 3)];
#pragma unroll
            for (int j2 = 0; j2 < 4; ++j2)
                bfr[j2] = *(const half8*)&buf[((AF + ((((wn << 2) | j2) << 1) | kc)) << 9) + (l << 3)];
#pragma unroll
            for (int i = 0; i < MRE; ++i)
#pragma unroll
                for (int j2 = 0; j2 < 4; ++j2)
                    acc[i][j2] = __builtin_amdgcn_mfma_f32_16x16x32_f16(
                        af[i], bfr[j2], acc[i][j2], 0, 0, 0);
        }
    };

    if constexpr (ASYNC) {
        int nk = K >> 6;
        // prologue: stage tiles 0..NBUF-2  (requires nk >= NBUF-1; K>=256 ok)
#pragma unroll
        for (int s = 0; s < NBUF - 1; ++s)
            stage(lds + s * TFS, s << 6);
        int cb = 0;                                    // buffer of tile t
        for (int t = 0; t < nk; ++t) {
            if constexpr (NBUF == 3) {
                if (t + 2 < nk) {
                    int sb = cb + 2; if (sb >= 3) sb -= 3;
                    stage(lds + sb * TFS, (t + 2) << 6);
                    asm volatile("s_waitcnt vmcnt(%0)" :: "i"(2 * LPW) : "memory");
                } else if (t + 1 < nk) {
                    asm volatile("s_waitcnt vmcnt(%0)" :: "i"(LPW) : "memory");
                } else {
                    asm volatile("s_waitcnt vmcnt(0)" ::: "memory");
                }
            } else {
                if (t + 1 < nk) {
                    stage(lds + (cb ^ 1) * TFS, (t + 1) << 6);
                    asm volatile("s_waitcnt vmcnt(%0)" :: "i"(LPW) : "memory");
                } else {
                    asm volatile("s_waitcnt vmcnt(0)" ::: "memory");
                }
            }
            __builtin_amdgcn_s_barrier();               // all waves' tile t in LDS
            asm volatile("" ::: "memory");
            compute(lds + cb * TFS);
            asm volatile("" ::: "memory");
            __builtin_amdgcn_s_barrier();               // tile-t buffer free
            asm volatile("" ::: "memory");
            cb = (cb + 1 == NBUF) ? 0 : cb + 1;
        }
    } else {
        for (int k0 = 0; k0 < K; k0 += 64) {
            stage(lds, k0);
            __syncthreads();
            compute(lds);
            __syncthreads();
        }
    }

    int colq = l & 15, rowq = (l >> 4) << 2;           // C/D map [m89/m91]
#pragma unroll
    for (int i = 0; i < MRE; ++i) {
        int gmb = m0 + (wm * MRE + i) * 16 + rowq;
#pragma unroll
        for (int j2 = 0; j2 < 4; ++j2) {
            int gn = n0 + ((wn << 2) | j2) * 16 + colq;
            float bv = bias ? bias[gn] : 0.f;
#pragma unroll
            for (int r = 0; r < 4; ++r) {
                float v = acc[i][j2][r] + bv;
                if (RELU) v = fmaxf(v, 0.f);
                if (OUTF16)
                    ((f16*)Cv)[(size_t)(gmb + r) * ldc + gn] = (f16)v;
                else
                    ((float*)Cv)[(size_t)(gmb + r) * ldc + gn] = v;
            }
        }
    }
}

// ---------------------------------------------------------------------------
// LayerNorm (ROUND-17): templated on input/residual precision. One WAVE per
// row, stats always computed in f32. Writes f16 (outh) and/or f32 (outf).
// ---------------------------------------------------------------------------
template <bool XF16, bool RESF16>
__global__ __launch_bounds__(256) void ln_k(
    const void* __restrict__ Xv, const void* __restrict__ resv,
    const int* __restrict__ map, const float* __restrict__ g,
    const float* __restrict__ beta, int nrows,
    f16* __restrict__ outh, float* __restrict__ outf)
{
    int r = blockIdx.x * 4 + (threadIdx.x >> 6);
    if (r >= nrows) return;
    int l = threadIdx.x & 63;
    float4 v;
    if constexpr (XF16) {
        half4 xh = *(const half4*)((const f16*)Xv + (size_t)r * DM + l * 4);
        v.x = (float)xh[0]; v.y = (float)xh[1]; v.z = (float)xh[2]; v.w = (float)xh[3];
    } else {
        v = *(const float4*)((const float*)Xv + (size_t)r * DM + l * 4);
    }
    {
        int rr = map ? map[r] : r;
        if constexpr (RESF16) {
            half4 rh = *(const half4*)((const f16*)resv + (size_t)rr * DM + l * 4);
            v.x += (float)rh[0]; v.y += (float)rh[1];
            v.z += (float)rh[2]; v.w += (float)rh[3];
        } else {
            float4 rv = *(const float4*)((const float*)resv + (size_t)rr * DM + l * 4);
            v.x += rv.x; v.y += rv.y; v.z += rv.z; v.w += rv.w;
        }
    }
    float s = v.x + v.y + v.z + v.w;
#pragma unroll
    for (int o = 32; o; o >>= 1) s += __shfl_xor(s, o);
    float mean = s * (1.f / 256.f);
    float dx = v.x - mean, dy = v.y - mean, dz = v.z - mean, dw = v.w - mean;
    float s2 = dx * dx + dy * dy + dz * dz + dw * dw;
#pragma unroll
    for (int o = 32; o; o >>= 1) s2 += __shfl_xor(s2, o);
    float rstd = 1.f / sqrtf(s2 * (1.f / 256.f) + 1e-5f);
    float4 gv = *(const float4*)(g + l * 4);
    float4 bv = *(const float4*)(beta + l * 4);
    float4 ov;
    ov.x = dx * rstd * gv.x + bv.x;
    ov.y = dy * rstd * gv.y + bv.y;
    ov.z = dz * rstd * gv.z + bv.z;
    ov.w = dw * rstd * gv.w + bv.w;
    if (outf) *(float4*)(outf + (size_t)r * DM + l * 4) = ov;
    if (outh) {
        half4 oh;
        oh[0] = (f16)ov.x; oh[1] = (f16)ov.y; oh[2] = (f16)ov.z; oh[3] = (f16)ov.w;
        *(half4*)(outh + (size_t)r * DM + l * 4) = oh;
    }
}

// ---------------------------------------------------------------------------
// Layer-0 attention, online-softmax prefix scan (f16 qkv, f16 packed out).
// ---------------------------------------------------------------------------
__global__ __launch_bounds__(256) void attn0_kernel(
    const f16* __restrict__ qkv, f16* __restrict__ ao)
{
    int bp = blockIdx.x;               // b*39 + p
    int b = bp / 39, p = bp % 39;
    int tid = threadIdx.x;
    int h = tid >> 6, l = tid & 63;

    float qv = (float)qkv[(size_t)(b * TS + p) * 768 + h * 64 + l];

    int krow = (l < 39) ? l : 38;
    const f16* Kr = qkv + (size_t)(b * TS + krow) * 768 + 256 + h * 64;
    float acc = 0.f;
#pragma unroll
    for (int c = 0; c < 8; ++c) {
        half8 k8 = *(const half8*)(Kr + c * 8);
#pragma unroll
        for (int j = 0; j < 8; ++j)
            acc += __shfl(qv, c * 8 + j) * (float)k8[j];
    }
    float s = acc * 0.125f;

    float m = -1e30f, lsum = 0.f, o = 0.f;
    for (int t = p; t < TM1; ++t) {
        float st = __shfl(s, t);
        float mnew = fmaxf(m, st);
        float c = __expf(m - mnew);
        float e = __expf(st - mnew);
        lsum = lsum * c + e;
        float vv = (float)qkv[(size_t)(b * TS + t) * 768 + 512 + h * 64 + l];
        o = o * c + e * vv;
        m = mnew;
        int row = ((t * (t + 1)) >> 1) + p;
        ao[((size_t)row * 32 + b) * DM + h * 64 + l] = (f16)(o / lsum);
    }
}

// ---------------------------------------------------------------------------
// Layer-1 attention. Block per (t,b): 4 waves = 4 heads. h1 row from h1h f16.
// ---------------------------------------------------------------------------
__global__ __launch_bounds__(256) void attn1_kernel(
    const f16* __restrict__ h1h, const f16* __restrict__ kv1,
    const f16* __restrict__ Wq, const float* __restrict__ bq,
    f16* __restrict__ ao1)
{
    int tb = blockIdx.x;
    int t = tb >> 5, b = tb & 31;
    int tid = threadIdx.x;
    int h = tid >> 6, l = tid & 63;
    int tri = (t * (t + 1)) >> 1;
    __shared__ float h1r[DM];
    h1r[tid] = (float)h1h[((size_t)(tri + t) * 32 + b) * DM + tid];
    __syncthreads();

    float q = bq[h * 64 + l];
    const half8* w8 = (const half8*)(Wq + (size_t)(h * 64 + l) * DM);
#pragma unroll 8
    for (int c = 0; c < 32; ++c) {
        half8 ww = w8[c];
#pragma unroll
        for (int j = 0; j < 8; ++j)
            q += (float)ww[j] * h1r[c * 8 + j];
    }

    int kr = (l <= t) ? l : t;
    const f16* Kp = kv1 + ((size_t)(tri + kr) * 32 + b) * 512 + h * 64;
    float sc = 0.f;
#pragma unroll
    for (int c = 0; c < 8; ++c) {
        half8 k8 = *(const half8*)(Kp + c * 8);
#pragma unroll
        for (int j = 0; j < 8; ++j)
            sc += __shfl(q, c * 8 + j) * (float)k8[j];
    }
    sc = (l <= t) ? sc * 0.125f : -1e30f;
    float m = sc;
#pragma unroll
    for (int o = 32; o; o >>= 1) m = fmaxf(m, __shfl_xor(m, o));
    float e = (l <= t) ? __expf(sc - m) : 0.f;
    float ss = e;
#pragma unroll
    for (int o = 32; o; o >>= 1) ss += __shfl_xor(ss, o);
    float a = e / ss;

    float o = 0.f;
    for (int k = 0; k <= t; ++k) {
        float ak = __shfl(a, k);
        o += ak * (float)kv1[((size_t)(tri + k) * 32 + b) * 512 + 256 + h * 64 + l];
    }
    ao1[(size_t)tb * DM + h * 64 + l] = (f16)o;
}

// ---------------------------------------------------------------------------
// Fast gelu via A&S 7.1.25 erf (|err| <= 5e-4, no exp).
// ---------------------------------------------------------------------------
__device__ __forceinline__ float gelu_f(float x)
{
    float ax = fabsf(x);
    float z  = ax * 0.70710678118654752440f;
    float d  = 1.f + z * (0.278393f + z * (0.230389f + z * (0.000972f + z * 0.078108f)));
    float d2 = d * d;
    float E  = 1.f - __builtin_amdgcn_rcpf(d2 * d2);
    return 0.5f * x + 0.5f * ax * E;
}

// ---------------------------------------------------------------------------
// out[b,p,t] = sigmoid( sum_k gelu(pp+cpb)*u + s )
// ROUND-19: 8-wave (512-thread), one t per wave, 2 acc chains. Verified r8
// (left top-5).
// ---------------------------------------------------------------------------
__global__ __launch_bounds__(512) void final_out(
    const f16* __restrict__ pp, const float* __restrict__ cpb,
    const float* __restrict__ u, const float* __restrict__ sv,
    float* __restrict__ out)
{
    // blockIdx.x = b*20 + pg*5 + tg   (32 * 4 * 5 = 640 blocks)
    int blk = blockIdx.x;
    int b  = blk / 20;
    int rr = blk - b * 20;
    int pg = rr / 5;
    int tg = rr - pg * 5;
    int tid = threadIdx.x;
    int w = tid >> 6, l = tid & 63;    // 8 waves

    __shared__ unsigned ldsT[128 * 64];   // [k2][p] packed f16x2 = 32 KB

    {   // stage-transpose 64p x 256k pp tile: lane = p row, wave = 32-k slice.
        const f16* rowp = pp + (size_t)((b << 8) + (pg << 6) + l) * DM + (w << 5);
#pragma unroll
        for (int j = 0; j < 4; ++j) {
            half8 h8 = *(const half8*)(rowp + j * 8);
#pragma unroll
            for (int j2 = 0; j2 < 4; ++j2) {
                union { f16 h[2]; unsigned v; } cv;
                cv.h[0] = h8[j2 * 2]; cv.h[1] = h8[j2 * 2 + 1];
                int k2 = (w << 4) + (j << 2) + j2;
                ldsT[(k2 << 6) + l] = cv.v;
            }
        }
    }
    __syncthreads();

    int t0  = tg * 8 + w;                              // wave's single t
    int tb0 = __builtin_amdgcn_readfirstlane(t0 * 32 + b);
    const float* cpa = cpb + (size_t)tb0 * DM;
    const float* ua  = u + (size_t)tb0 * DM;

    float accx = 0.f, accy = 0.f;                      // 2 independent chains
#pragma unroll 8
    for (int k2 = 0; k2 < 128; ++k2) {
        union { unsigned v; f16 h[2]; } pr;
        pr.v = ldsT[(k2 << 6) + l];
        float a0 = (float)pr.h[0], a1 = (float)pr.h[1];
        float2 c0 = *(const float2*)(cpa + (k2 << 1));
        float2 u0 = *(const float2*)(ua + (k2 << 1));
        accx += gelu_f(a0 + c0.x) * u0.x;
        accy += gelu_f(a1 + c0.y) * u0.y;
    }
    float s0 = sv[tb0];
    int op = ((b << 8) + (pg << 6) + l) * TS;
    out[op + t0] = 1.f / (1.f + __expf(-(accx + accy + s0)));
}

// ---------------------------------------------------------------------------
// Launcher
// ---------------------------------------------------------------------------
extern "C" void kernel_launch(void* const* d_in, const int* in_sizes, int n_in,
                              void* d_out, int out_size, void* d_ws, size_t ws_size,
                              hipStream_t stream)
{
    (void)in_sizes; (void)n_in; (void)out_size;
    const float* patches   = (const float*)d_in[0];
    const int*   tokens    = (const int*)  d_in[1];
    const float* embedding = (const float*)d_in[2];
    const float* pos_emb   = (const float*)d_in[3];
    const float* in_proj_w = (const float*)d_in[4];
    const float* in_proj_b = (const float*)d_in[5];
    const float* out_proj_w= (const float*)d_in[6];
    const float* out_proj_b= (const float*)d_in[7];
    const float* lin1_w    = (const float*)d_in[8];
    const float* lin1_b    = (const float*)d_in[9];
    const float* lin2_w    = (const float*)d_in[10];
    const float* lin2_b    = (const float*)d_in[11];
    const float* ln1_g     = (const float*)d_in[12];
    const float* ln1_b     = (const float*)d_in[13];
    const float* ln2_g     = (const float*)d_in[14];
    const float* ln2_b     = (const float*)d_in[15];
    const float* fus_w1    = (const float*)d_in[16];
    const float* fus_b1    = (const float*)d_in[17];
    const float* fus_w2    = (const float*)d_in[18];
    const float* fus_b2    = (const float*)d_in[19];
    const float* cls_w     = (const float*)d_in[20];
    const float* cls_b     = (const float*)d_in[21];

    if (ws_size < (size_t)WS_FLOATS * 4) return;

    float* ws   = (float*)d_ws;
    f16*   embh = (f16*)(ws + OFF_EMBH);
    float* emb  = ws + OFF_EMB;           // dead (kept for layout stability)
    f16*   qkvh = (f16*)(ws + OFF_QKVH);
    f16*   x1p  = (f16*)(ws + OFF_X1);    // pre-LN attn-block out (f16)
    f16*   x1h  = (f16*)(ws + OFF_X1H);   // ln1 out (f16)
    f16*   pph  = (f16*)(ws + OFF_X1H);   // aliases x1h head (x1h dead after ln2)
    f16*   h1p  = (f16*)(ws + OFF_H1);    // pre-LN ffn out (f16)
    float* big  = ws + OFF_BIG;
    f16*   ao0h = (f16*)big;              // head; dead after out-proj0
    f16*   ff1h = (f16*)big;              // spans ALL of big; dead after lin2
    f16*   kv1h = (f16*)big;              // head; dead after attn1
    f16*   ao1h = (f16*)(big + BT_AO1H);
    float* x2   = big + BT_X2;
    f16*   x2h  = (f16*)(big + BT_X2H);
    f16*   ff2h = (f16*)(big + BT_FF2H);
    f16*   h1h  = (f16*)(big + BT_H1H);   // ln2 out (f16): kv/attn1/ln-x2 res
    float* ctx  = ws + OFF_CTX;           // dedicated; rows 0..31 zeroed by prep
    float* cpb  = ws + OFF_CPB;
    float* u    = ws + OFF_U;
    float* svec = ws + OFF_S;
    f16*   wqkvh= (f16*)(ws + OFF_WQKVH);
    f16*   wq1h = (f16*)(ws + OFF_WQ1H);
    f16*   kvwh = (f16*)(ws + OFF_KVWH);
    f16*   woh  = (f16*)(ws + OFF_WOH);
    f16*   woh1 = (f16*)(ws + OFF_WOH1);
    f16*   l1wh = (f16*)(ws + OFF_L1WH);
    f16*   l1wh1= (f16*)(ws + OFF_L1WH1);
    f16*   l2wh = (f16*)(ws + OFF_L2WH);
    f16*   l2wh1= (f16*)(ws + OFF_L2WH1);
    f16*   w1ph = (f16*)(ws + OFF_W1PH);
    f16*   w1ch = (f16*)(ws + OFF_W1CH);
    f16*   fw2th= (f16*)(ws + OFF_FW2TH);
    f16*   cwgh = (f16*)(ws + OFF_CWGH);
    int*   map1 = (int*)(ws + OFF_MAP);
    int*   map2 = map1 + NTOK;

    prep_kernel<<<10050, 256, 0, stream>>>(
        tokens, embedding, pos_emb, in_proj_w, out_proj_w, lin1_w, lin2_w,
        fus_w1, fus_w2, cls_w, cls_b, fus_b2,
        emb, embh, wqkvh, wq1h, kvwh, woh, woh1, l1wh, l1wh1, l2wh, l2wh1,
        w1ph, w1ch, fw2th, cwgh, svec, ctx, map1, map2);

    // u = cwg @ fw2t^T : M=1280(20x64), N=256(2), K=256 (u dedicated — safe early)
    gemm_x<64, 3, f16, false, false><<<dim3(2, 20), 256, 0, stream>>>(
        cwgh, DM, fw2th, DM, nullptr, u, DM, DM);

    // ---- Layer 0 ----
    gemm_x<64, 3, f16, false, true><<<dim3(6, 20), 256, 0, stream>>>(
        embh, DM, wqkvh, DM, in_proj_b, qkvh, 768, DM);
    attn0_kernel<<<NQ2, 256, 0, stream>>>(qkvh, ao0h);
    // out-proj0 -> x1p (f16 pre-LN); BM=128 (r6)
    gemm_x<128, 2, f16, false, true><<<dim3(2, 195), 256, 0, stream>>>(
        ao0h, DM, woh, DM, out_proj_b, x1p, DM, DM);
    // ln1: x1h = LN(x1p + embh[map1])
    ln_k<true, true><<<6240, 256, 0, stream>>>(
        x1p, embh, map1, ln1_g, ln1_b, NTOK, x1h, nullptr);
    gemm_x<128, 2, f16, true, true><<<dim3(8, 195), 256, 0, stream>>>(
        x1h, DM, l1wh, DM, lin1_b, ff1h, DFF, DM);
    // lin2 -> h1p (f16 pre-LN); BM=128 (r6)
    gemm_x<128, 2, f16, false, true><<<dim3(2, 195), 256, 0, stream>>>(
        ff1h, DFF, l2wh, DFF, lin2_b, h1p, DM, DFF);
    // ln2: h1h = LN(h1p + x1h)   (h1h in big tail; ff1h dead now)
    ln_k<true, true><<<6240, 256, 0, stream>>>(
        h1p, x1h, nullptr, ln2_g, ln2_b, NTOK, h1h, nullptr);

    // pp: M=8192(128x64), N=256(2), K=384 (x1h head free AFTER ln2 -> pph)
    gemm_x<64, 1, float, false, true><<<dim3(2, 128), 256, 0, stream>>>(
        patches, DINO, w1ph, DINO, nullptr, pph, DM, DINO);

    // ---- Layer 1 ----
    // K/V: A = h1h f16 async, N=512(4) -> kv1h (big head; disjoint from h1h tail)
    gemm_x<128, 2, f16, false, true><<<dim3(4, 195), 256, 0, stream>>>(
        h1h, DM, kvwh, DM, in_proj_b + 768 + 256, kv1h, 512, DM);
    attn1_kernel<<<NQ2, 256, 0, stream>>>(
        h1h, kv1h, wq1h, in_proj_b + 768, ao1h);
    // out-proj1 (MFMA, M padded to 1280; pad rows garbage, never read)
    gemm_x<64, 3, f16, false, false><<<dim3(2, 20), 256, 0, stream>>>(
        ao1h, DM, woh1, DM, out_proj_b + DM, x2, DM, DM);
    // ln(x2): res = h1h[map2] (f16); writes x2 (f32, residual for ln-ctx) + x2h
    ln_k<false, true><<<312, 256, 0, stream>>>(
        x2, h1h, map2, ln1_g + DM, ln1_b + DM, NQ2, x2h, x2);
    gemm_x<64, 3, f16, true, true><<<dim3(8, 20), 256, 0, stream>>>(
        x2h, DM, l1wh1, DM, lin1_b + DFF, ff2h, DFF, DM);
    // pad rows spill 8192 floats into cpb head; cpb-gemm rewrites cpb below
    gemm_x<64, 3, f16, false, false><<<dim3(2, 20), 256, 0, stream>>>(
        ff2h, DFF, l2wh1, DFF, lin2_b + DM, ctx + BB * DM, DM, DFF);
    // ln(ctx): res = x2 (f32); f32 in-place (cpb-gemm reads ctx as float)
    ln_k<false, false><<<312, 256, 0, stream>>>(
        ctx + BB * DM, x2, nullptr, ln2_g + DM, ln2_b + DM, NQ2, nullptr,
        ctx + BB * DM);

    // cpb = ctx @ w1c^T + fus_b1 : M=1280(20x64), N=256(2), K=256
    gemm_x<64, 1, float, false, false><<<dim3(2, 20), 256, 0, stream>>>(
        ctx, DM, w1ch, DM, fus_b1, cpb, DM, DM);

    final_out<<<640, 512, 0, stream>>>(pph, cpb, u, svec, (float*)d_out);
}

// Round 10
// 401.900 us; speedup vs baseline: 1.0441x; 1.0265x over previous
//
#include <hip/hip_runtime.h>
#include <math.h>

// ---------------------------------------------------------------------------
// Problem constants
// ---------------------------------------------------------------------------
#define DM    256     // D_MODEL
#define NH    4
#define HD    64
#define TS    40
#define TM1   39
#define BB    32
#define DFF   1024
#define DINO  384
#define NPATCH 256
#define VOCAB 4096

#define NTOK  24960   // 780*32 packed (t, p<=t, b) tokens
#define NQ2   1248    // 39*32

typedef _Float16 f16;
typedef __attribute__((ext_vector_type(8))) _Float16 half8;  // MFMA A/B frag
typedef __attribute__((ext_vector_type(4))) _Float16 half4;
typedef __attribute__((ext_vector_type(4))) float f32x4;

// ---------------------------------------------------------------------------
// Workspace layout (float offsets), 127.25 MB total (< 127.57 proven budget).
// ROUND-17: f16 activation chain (x1p/x1h/h1p/h1h) — verified r5.
// ROUND-18: out-proj0 & lin2 -> BM=128 — verified r6 (left top-5).
// ROUND-19: final_out 8-wave restructure — partial (+1 us only; r9 showed
// VALU-floor-bound, not TLP-bound).
// ROUND-20: bijective XCD-chunked swizzle — verified r8 (lin1 FETCH 50->8.6MB).
// ROUND-21: final_out sigmoid-gelu (3x fewer VALU; see gelu_f comment).
// ---------------------------------------------------------------------------
#define OFF_EMBH   0u          /* f16 1280*256  = 327680 h -> 163840 fl */
#define OFF_EMB    163840u     /* f32 1280*256  -> 327680 fl (dead; kept) */
#define OFF_QKVH   491520u     /* f16 1280*768  = 983040 h -> 491520 fl */
#define OFF_X1     983040u     /* x1p: f16 24960*256 (pre-LN attn-block out) */
#define OFF_X1H    7372800u    /* f16 24960*256 (ln1 out); pph aliases head */
#define OFF_H1     10567680u   /* h1p: f16 24960*256 (pre-LN ffn out) */
#define OFF_BIG    16957440u   /* 12779520 fl */
/* big interior (float offsets from big):
     head [0,6389760)         : ao0h (attn0..outproj0) / ff1h spans ALL of big
                                (lin1..lin2) / kv1h (kv..attn1)
     BT_AO1H  [6389760,6553600)   f16 1280*256, written by attn1
     BT_X2    [6553600,6881280)   f32 1280*256, written by out-proj1
     BT_X2H   [6881280,7045120)   f16 1280*256, written by ln(x2)
     BT_FF2H  [7045120,7700480)   f16 1280*1024, written by lin1-l1
     BT_H1H   [7700480,10895360)  f16 24960*256, written by ln2 (post-lin2),
                                  read by kv-gemm/attn1/ln-x2 residual. */
#define   BT_AO1H  6389760u
#define   BT_X2    6553600u
#define   BT_X2H   6881280u
#define   BT_FF2H  7045120u
#define   BT_H1H   7700480u
#define OFF_CTX    29736960u   /* f32 1280*256 -> 327680 fl (rows 0..31 zeroed by prep) */
#define OFF_CPB    30064640u   /* f32 1280*256 (lin2-l1 pad spill lands here; rewritten) */
#define OFF_U      30392320u   /* f32 1280*256 (dedicated) */
#define OFF_S      30720000u   /* f32 2048 fl */
#define OFF_WQKVH  30722048u   /* f16 768*256 */
#define OFF_WQ1H   30820352u   /* f16 256*256 */
#define OFF_KVWH   30853120u   /* f16 512*256 */
#define OFF_WOH    30918656u   /* f16 256*256 */
#define OFF_WOH1   30951424u   /* f16 256*256 */
#define OFF_L1WH   30984192u   /* f16 1024*256 */
#define OFF_L1WH1  31115264u   /* f16 1024*256 */
#define OFF_L2WH   31246336u   /* f16 256*1024 */
#define OFF_L2WH1  31377408u   /* f16 256*1024 */
#define OFF_W1PH   31508480u   /* f16 256*384 */
#define OFF_W1CH   31557632u   /* f16 256*256 */
#define OFF_FW2TH  31590400u   /* f16 256*256 */
#define OFF_CWGH   31623168u   /* f16 1280*256 */
#define OFF_MAP    31787008u   /* int 24960+1248 */
#define WS_FLOATS  31813216u   /* = 127.25 MB < 127.57 known-good */

// ---------------------------------------------------------------------------
// prep: embed | all weight f16 conversions | w1p/w1c/fw2t gathers | cls
// gather | s vector | ctx t=0 zeros | maps.
// ---------------------------------------------------------------------------
__global__ __launch_bounds__(256) void prep_kernel(
    const int* __restrict__ tokens, const float* __restrict__ etab,
    const float* __restrict__ pos,
    const float* __restrict__ ipw, const float* __restrict__ opw,
    const float* __restrict__ l1w, const float* __restrict__ l2w,
    const float* __restrict__ fw1, const float* __restrict__ fw2,
    const float* __restrict__ clsw, const float* __restrict__ clsb,
    const float* __restrict__ fb2,
    float* __restrict__ emb, f16* __restrict__ embh,
    f16* __restrict__ wqkvh, f16* __restrict__ wq1h, f16* __restrict__ kvwh,
    f16* __restrict__ woh, f16* __restrict__ woh1,
    f16* __restrict__ l1wh, f16* __restrict__ l1wh1,
    f16* __restrict__ l2wh, f16* __restrict__ l2wh1,
    f16* __restrict__ w1ph, f16* __restrict__ w1ch, f16* __restrict__ fw2th,
    f16* __restrict__ cwgh, float* __restrict__ sv, float* __restrict__ ctx,
    int* __restrict__ map1, int* __restrict__ map2)
{
    int i = blockIdx.x * 256 + threadIdx.x;
    if (i < 327680) {                       // embed
        int r = i >> 8, j = i & 255;
        int p = r % TS;
        float v = etab[(size_t)tokens[r] * DM + j] + pos[p * DM + j];
        emb[i] = v; embh[i] = (f16)v;
        return;
    }
    i -= 327680;
    if (i < 196608) { wqkvh[i] = (f16)ipw[i]; return; }
    i -= 196608;
    if (i < 65536)  { wq1h[i] = (f16)ipw[196608 + i]; return; }
    i -= 65536;
    if (i < 131072) { kvwh[i] = (f16)ipw[262144 + i]; return; }
    i -= 131072;
    if (i < 65536)  { woh[i]  = (f16)opw[i]; return; }
    i -= 65536;
    if (i < 65536)  { woh1[i] = (f16)opw[65536 + i]; return; }
    i -= 65536;
    if (i < 262144) { l1wh[i]  = (f16)l1w[i]; return; }
    i -= 262144;
    if (i < 262144) { l1wh1[i] = (f16)l1w[262144 + i]; return; }
    i -= 262144;
    if (i < 262144) { l2wh[i]  = (f16)l2w[i]; return; }
    i -= 262144;
    if (i < 262144) { l2wh1[i] = (f16)l2w[262144 + i]; return; }
    i -= 262144;
    if (i < 98304) {                        // w1p (strided gather)
        int r = i / 384, c = i - r * 384;
        w1ph[i] = (f16)fw1[r * 640 + c];
        return;
    }
    i -= 98304;
    if (i < 65536) {                        // w1c (strided gather)
        int n = i >> 8, k = i & 255;
        w1ch[i] = (f16)fw1[n * 640 + 384 + k];
        return;
    }
    i -= 65536;
    if (i < 65536) {                        // fw2 transpose: fw2t[j,k]=fw2[k,j]
        int j = i >> 8, k = i & 255;
        fw2th[i] = (f16)fw2[k * 256 + j];
        return;
    }
    i -= 65536;
    if (i < 327680) {                       // cls gather: cwgh[tb,:] = cls_w[tok(t,b)]
        int tb = i >> 8, j = i & 255;
        int t = tb >> 5, b = tb & 31;
        cwgh[i] = (f16)clsw[(size_t)tokens[b * TS + t] * DM + j];
        return;
    }
    i -= 327680;
    if (i < 81920) {                        // s[tb] = fb2 . cls_w[tok] + clsb[tok]
        int tb = i >> 6, l = i & 63;
        int t = tb >> 5, b = tb & 31;
        int tok = tokens[b * TS + t];
        float a = 0.f;
#pragma unroll
        for (int c = 0; c < 4; ++c)
            a += fb2[l + 64 * c] * clsw[(size_t)tok * DM + l + 64 * c];
#pragma unroll
        for (int o = 32; o; o >>= 1) a += __shfl_xor(a, o);
        if (l == 0) sv[tb] = a + clsb[tok];
        return;
    }
    i -= 81920;
    if (i < 8192) { ctx[i] = 0.f; return; } // ctx rows t=0 (dedicated region)
    i -= 8192;
    if (i < NQ2) {
        int t = i >> 5, b = i & 31;
        map2[i] = ((t * (t + 1)) / 2 + t) * 32 + b;
    }
    if (i < NTOK) {
        int q = i >> 5, b = i & 31;
        int t = 0;
        while (((t + 1) * (t + 2)) / 2 <= q) ++t;
        int p = q - (t * (t + 1)) / 2;
        map1[i] = b * TS + p;
    }
}

// ---------------------------------------------------------------------------
// async 16B/lane global->LDS stage (wave-uniform LDS base) [m97/m104]
// ---------------------------------------------------------------------------
__device__ __forceinline__ void stage16(const f16* g, f16* lbase_wave_uniform) {
    __builtin_amdgcn_global_load_lds(
        (const __attribute__((address_space(1))) void*)g,
        (__attribute__((address_space(3))) void*)lbase_wave_uniform, 16, 0, 0);
}

__device__ __forceinline__ half8 load_frag8(const float* p) {
    float4 a0 = *(const float4*)p;
    float4 a1 = *(const float4*)(p + 4);
    half8 h;
    h[0] = (f16)a0.x; h[1] = (f16)a0.y; h[2] = (f16)a0.z; h[3] = (f16)a0.w;
    h[4] = (f16)a1.x; h[5] = (f16)a1.y; h[6] = (f16)a1.z; h[7] = (f16)a1.w;
    return h;
}

// ---------------------------------------------------------------------------
// MFMA GEMM: BM x 128 tile, 4 waves, balanced frag mapping. NBUF-deep async
// pipeline with counted vmcnt gates. (R18: NTOK-row GEMMs at BM=128.)
// ROUND-20: bijective XCD-chunked swizzle (T1/m204) — verified r8: lin1
// FETCH 50.5 -> 8.6 MB (same-A-row blocks share one XCD L2; L3 absorbs the
// rest), dur -12%. Pure index bijection, no sync-structure change.
// ---------------------------------------------------------------------------
template <int BM, int NBUF, typename TA, bool RELU, bool OUTF16>
__global__ __launch_bounds__(256) void gemm_x(
    const TA* __restrict__ A, int lda,
    const f16* __restrict__ B, int ldb,
    const float* __restrict__ bias,
    void* __restrict__ Cv, int ldc, int K)
{
    constexpr int AF  = BM / 8;       // # A frags
    constexpr int TF  = AF + 16;      // total frags
    constexpr int MRE = BM / 32;      // acc rows per wave
    constexpr int LPW = TF / 4;       // global_load_lds issued per wave per tile
    constexpr int TFS = TF * 512;     // f16 elems per buffer
    constexpr bool ASYNC = __is_same(TA, f16);
    __shared__ __align__(16) f16 lds[(ASYNC ? NBUF : 1) * TFS];
    int tid = threadIdx.x;
    int w = tid >> 6, l = tid & 63;

    // ---- XCD-chunked bijective swizzle (m204) ----
    int gx  = gridDim.x;
    int nwg = gx * gridDim.y;
    int d   = blockIdx.y * gx + blockIdx.x;
    int q8  = nwg >> 3, r8 = nwg & 7;
    int c8  = d & 7, j8 = d >> 3;
    int lid = (c8 < r8 ? c8 * (q8 + 1) : r8 * (q8 + 1) + (c8 - r8) * q8) + j8;
    int m0 = (lid / gx) * BM, n0 = (lid % gx) << 7;

    int lrow = l & 15;
    int lk8  = (l >> 4) << 3;
    int wm = w >> 1, wn = w & 1;

    f32x4 acc[MRE][4] = {};

    auto stage = [&](f16* dst, int k0) {
#pragma unroll
        for (int j = 0; j < TF / 4; ++j) {
            int f = (j << 2) | w;                      // balanced across waves
            if (f < AF) {
                int mi = f >> 1, kc = f & 1;
                const TA* ga = A + (size_t)(m0 + (mi << 4) + lrow) * lda + k0 + (kc << 5) + lk8;
                if constexpr (ASYNC) {
                    stage16((const f16*)ga, dst + (f << 9));
                } else {
                    *(half8*)&dst[(f << 9) + (l << 3)] = load_frag8((const float*)ga);
                }
            } else {
                int fb = f - AF;
                int nj = fb >> 1, kc = fb & 1;
                const f16* gb = B + (size_t)(n0 + (nj << 4) + lrow) * ldb + k0 + (kc << 5) + lk8;
                stage16(gb, dst + (f << 9));
            }
        }
    };

    auto compute = [&](const f16* buf) {
#pragma unroll
        for (int kc = 0; kc < 2; ++kc) {
            half8 af[MRE], bfr[4];
#pragma unroll
            for (int i = 0; i < MRE; ++i)
                af[i] = *(const half8*)&buf[((((wm * MRE + i) << 1) | kc) << 9) + (l << 3)];
#pragma unroll
            for (int j2 = 0; j2 < 4; ++j2)
                bfr[j2] = *(const half8*)&buf[((AF + ((((wn << 2) | j2) << 1) | kc)) << 9) + (l << 3)];
#pragma unroll
            for (int i = 0; i < MRE; ++i)
#pragma unroll
                for (int j2 = 0; j2 < 4; ++j2)
                    acc[i][j2] = __builtin_amdgcn_mfma_f32_16x16x32_f16(
                        af[i], bfr[j2], acc[i][j2], 0, 0, 0);
        }
    };

    if constexpr (ASYNC) {
        int nk = K >> 6;
        // prologue: stage tiles 0..NBUF-2  (requires nk >= NBUF-1; K>=256 ok)
#pragma unroll
        for (int s = 0; s < NBUF - 1; ++s)
            stage(lds + s * TFS, s << 6);
        int cb = 0;                                    // buffer of tile t
        for (int t = 0; t < nk; ++t) {
            if constexpr (NBUF == 3) {
                if (t + 2 < nk) {
                    int sb = cb + 2; if (sb >= 3) sb -= 3;
                    stage(lds + sb * TFS, (t + 2) << 6);
                    asm volatile("s_waitcnt vmcnt(%0)" :: "i"(2 * LPW) : "memory");
                } else if (t + 1 < nk) {
                    asm volatile("s_waitcnt vmcnt(%0)" :: "i"(LPW) : "memory");
                } else {
                    asm volatile("s_waitcnt vmcnt(0)" ::: "memory");
                }
            } else {
                if (t + 1 < nk) {
                    stage(lds + (cb ^ 1) * TFS, (t + 1) << 6);
                    asm volatile("s_waitcnt vmcnt(%0)" :: "i"(LPW) : "memory");
                } else {
                    asm volatile("s_waitcnt vmcnt(0)" ::: "memory");
                }
            }
            __builtin_amdgcn_s_barrier();               // all waves' tile t in LDS
            asm volatile("" ::: "memory");
            compute(lds + cb * TFS);
            asm volatile("" ::: "memory");
            __builtin_amdgcn_s_barrier();               // tile-t buffer free
            asm volatile("" ::: "memory");
            cb = (cb + 1 == NBUF) ? 0 : cb + 1;
        }
    } else {
        for (int k0 = 0; k0 < K; k0 += 64) {
            stage(lds, k0);
            __syncthreads();
            compute(lds);
            __syncthreads();
        }
    }

    int colq = l & 15, rowq = (l >> 4) << 2;           // C/D map [m89/m91]
#pragma unroll
    for (int i = 0; i < MRE; ++i) {
        int gmb = m0 + (wm * MRE + i) * 16 + rowq;
#pragma unroll
        for (int j2 = 0; j2 < 4; ++j2) {
            int gn = n0 + ((wn << 2) | j2) * 16 + colq;
            float bv = bias ? bias[gn] : 0.f;
#pragma unroll
            for (int r = 0; r < 4; ++r) {
                float v = acc[i][j2][r] + bv;
                if (RELU) v = fmaxf(v, 0.f);
                if (OUTF16)
                    ((f16*)Cv)[(size_t)(gmb + r) * ldc + gn] = (f16)v;
                else
                    ((float*)Cv)[(size_t)(gmb + r) * ldc + gn] = v;
            }
        }
    }
}

// ---------------------------------------------------------------------------
// LayerNorm (ROUND-17): templated on input/residual precision. One WAVE per
// row, stats always computed in f32. Writes f16 (outh) and/or f32 (outf).
// ---------------------------------------------------------------------------
template <bool XF16, bool RESF16>
__global__ __launch_bounds__(256) void ln_k(
    const void* __restrict__ Xv, const void* __restrict__ resv,
    const int* __restrict__ map, const float* __restrict__ g,
    const float* __restrict__ beta, int nrows,
    f16* __restrict__ outh, float* __restrict__ outf)
{
    int r = blockIdx.x * 4 + (threadIdx.x >> 6);
    if (r >= nrows) return;
    int l = threadIdx.x & 63;
    float4 v;
    if constexpr (XF16) {
        half4 xh = *(const half4*)((const f16*)Xv + (size_t)r * DM + l * 4);
        v.x = (float)xh[0]; v.y = (float)xh[1]; v.z = (float)xh[2]; v.w = (float)xh[3];
    } else {
        v = *(const float4*)((const float*)Xv + (size_t)r * DM + l * 4);
    }
    {
        int rr = map ? map[r] : r;
        if constexpr (RESF16) {
            half4 rh = *(const half4*)((const f16*)resv + (size_t)rr * DM + l * 4);
            v.x += (float)rh[0]; v.y += (float)rh[1];
            v.z += (float)rh[2]; v.w += (float)rh[3];
        } else {
            float4 rv = *(const float4*)((const float*)resv + (size_t)rr * DM + l * 4);
            v.x += rv.x; v.y += rv.y; v.z += rv.z; v.w += rv.w;
        }
    }
    float s = v.x + v.y + v.z + v.w;
#pragma unroll
    for (int o = 32; o; o >>= 1) s += __shfl_xor(s, o);
    float mean = s * (1.f / 256.f);
    float dx = v.x - mean, dy = v.y - mean, dz = v.z - mean, dw = v.w - mean;
    float s2 = dx * dx + dy * dy + dz * dz + dw * dw;
#pragma unroll
    for (int o = 32; o; o >>= 1) s2 += __shfl_xor(s2, o);
    float rstd = 1.f / sqrtf(s2 * (1.f / 256.f) + 1e-5f);
    float4 gv = *(const float4*)(g + l * 4);
    float4 bv = *(const float4*)(beta + l * 4);
    float4 ov;
    ov.x = dx * rstd * gv.x + bv.x;
    ov.y = dy * rstd * gv.y + bv.y;
    ov.z = dz * rstd * gv.z + bv.z;
    ov.w = dw * rstd * gv.w + bv.w;
    if (outf) *(float4*)(outf + (size_t)r * DM + l * 4) = ov;
    if (outh) {
        half4 oh;
        oh[0] = (f16)ov.x; oh[1] = (f16)ov.y; oh[2] = (f16)ov.z; oh[3] = (f16)ov.w;
        *(half4*)(outh + (size_t)r * DM + l * 4) = oh;
    }
}

// ---------------------------------------------------------------------------
// Layer-0 attention, online-softmax prefix scan (f16 qkv, f16 packed out).
// ---------------------------------------------------------------------------
__global__ __launch_bounds__(256) void attn0_kernel(
    const f16* __restrict__ qkv, f16* __restrict__ ao)
{
    int bp = blockIdx.x;               // b*39 + p
    int b = bp / 39, p = bp % 39;
    int tid = threadIdx.x;
    int h = tid >> 6, l = tid & 63;

    float qv = (float)qkv[(size_t)(b * TS + p) * 768 + h * 64 + l];

    int krow = (l < 39) ? l : 38;
    const f16* Kr = qkv + (size_t)(b * TS + krow) * 768 + 256 + h * 64;
    float acc = 0.f;
#pragma unroll
    for (int c = 0; c < 8; ++c) {
        half8 k8 = *(const half8*)(Kr + c * 8);
#pragma unroll
        for (int j = 0; j < 8; ++j)
            acc += __shfl(qv, c * 8 + j) * (float)k8[j];
    }
    float s = acc * 0.125f;

    float m = -1e30f, lsum = 0.f, o = 0.f;
    for (int t = p; t < TM1; ++t) {
        float st = __shfl(s, t);
        float mnew = fmaxf(m, st);
        float c = __expf(m - mnew);
        float e = __expf(st - mnew);
        lsum = lsum * c + e;
        float vv = (float)qkv[(size_t)(b * TS + t) * 768 + 512 + h * 64 + l];
        o = o * c + e * vv;
        m = mnew;
        int row = ((t * (t + 1)) >> 1) + p;
        ao[((size_t)row * 32 + b) * DM + h * 64 + l] = (f16)(o / lsum);
    }
}

// ---------------------------------------------------------------------------
// Layer-1 attention. Block per (t,b): 4 waves = 4 heads. h1 row from h1h f16.
// ---------------------------------------------------------------------------
__global__ __launch_bounds__(256) void attn1_kernel(
    const f16* __restrict__ h1h, const f16* __restrict__ kv1,
    const f16* __restrict__ Wq, const float* __restrict__ bq,
    f16* __restrict__ ao1)
{
    int tb = blockIdx.x;
    int t = tb >> 5, b = tb & 31;
    int tid = threadIdx.x;
    int h = tid >> 6, l = tid & 63;
    int tri = (t * (t + 1)) >> 1;
    __shared__ float h1r[DM];
    h1r[tid] = (float)h1h[((size_t)(tri + t) * 32 + b) * DM + tid];
    __syncthreads();

    float q = bq[h * 64 + l];
    const half8* w8 = (const half8*)(Wq + (size_t)(h * 64 + l) * DM);
#pragma unroll 8
    for (int c = 0; c < 32; ++c) {
        half8 ww = w8[c];
#pragma unroll
        for (int j = 0; j < 8; ++j)
            q += (float)ww[j] * h1r[c * 8 + j];
    }

    int kr = (l <= t) ? l : t;
    const f16* Kp = kv1 + ((size_t)(tri + kr) * 32 + b) * 512 + h * 64;
    float sc = 0.f;
#pragma unroll
    for (int c = 0; c < 8; ++c) {
        half8 k8 = *(const half8*)(Kp + c * 8);
#pragma unroll
        for (int j = 0; j < 8; ++j)
            sc += __shfl(q, c * 8 + j) * (float)k8[j];
    }
    sc = (l <= t) ? sc * 0.125f : -1e30f;
    float m = sc;
#pragma unroll
    for (int o = 32; o; o >>= 1) m = fmaxf(m, __shfl_xor(m, o));
    float e = (l <= t) ? __expf(sc - m) : 0.f;
    float ss = e;
#pragma unroll
    for (int o = 32; o; o >>= 1) ss += __shfl_xor(ss, o);
    float a = e / ss;

    float o = 0.f;
    for (int k = 0; k <= t; ++k) {
        float ak = __shfl(a, k);
        o += ak * (float)kv1[((size_t)(tri + k) * 32 + b) * 512 + 256 + h * 64 + l];
    }
    ao1[(size_t)tb * DM + h * 64 + l] = (f16)o;
}

// ---------------------------------------------------------------------------
// ROUND-21 gelu: x*sigmoid(1.702x) = x * rcp(1 + exp2(-2.4551x)).
// 4 VALU + 2 trans per eval vs the A&S erf form's ~12 VALU + 1 trans.
// R9 counters showed final_out VALU-floor-bound (VALUBusy 57% at Occ 29.5%,
// dur unchanged vs 4-wave) — instruction count, not TLP, is the limit.
// Precision: pointwise |err| <= 0.010; u ~ 6e-3 scale, 256 random-sign
// terms -> logit shift ~9e-4 -> prob shift <= 2.3e-4, an order below the
// passing absmax 3.9e-3. (Used ONLY in final_out.)
// ---------------------------------------------------------------------------
__device__ __forceinline__ float gelu_f(float x)
{
    // -1.702 * log2(e) = -2.4550744
    float e = __builtin_amdgcn_exp2f(-2.4550744f * x);
    return x * __builtin_amdgcn_rcpf(1.f + e);
}

// ---------------------------------------------------------------------------
// out[b,p,t] = sigmoid( sum_k gelu(pp+cpb)*u + s )
// ROUND-19: 8-wave (512-thread), one t per wave, 2 acc chains.
// ---------------------------------------------------------------------------
__global__ __launch_bounds__(512) void final_out(
    const f16* __restrict__ pp, const float* __restrict__ cpb,
    const float* __restrict__ u, const float* __restrict__ sv,
    float* __restrict__ out)
{
    // blockIdx.x = b*20 + pg*5 + tg   (32 * 4 * 5 = 640 blocks)
    int blk = blockIdx.x;
    int b  = blk / 20;
    int rr = blk - b * 20;
    int pg = rr / 5;
    int tg = rr - pg * 5;
    int tid = threadIdx.x;
    int w = tid >> 6, l = tid & 63;    // 8 waves

    __shared__ unsigned ldsT[128 * 64];   // [k2][p] packed f16x2 = 32 KB

    {   // stage-transpose 64p x 256k pp tile: lane = p row, wave = 32-k slice.
        const f16* rowp = pp + (size_t)((b << 8) + (pg << 6) + l) * DM + (w << 5);
#pragma unroll
        for (int j = 0; j < 4; ++j) {
            half8 h8 = *(const half8*)(rowp + j * 8);
#pragma unroll
            for (int j2 = 0; j2 < 4; ++j2) {
                union { f16 h[2]; unsigned v; } cv;
                cv.h[0] = h8[j2 * 2]; cv.h[1] = h8[j2 * 2 + 1];
                int k2 = (w << 4) + (j << 2) + j2;
                ldsT[(k2 << 6) + l] = cv.v;
            }
        }
    }
    __syncthreads();

    int t0  = tg * 8 + w;                              // wave's single t
    int tb0 = __builtin_amdgcn_readfirstlane(t0 * 32 + b);
    const float* cpa = cpb + (size_t)tb0 * DM;
    const float* ua  = u + (size_t)tb0 * DM;

    float accx = 0.f, accy = 0.f;                      // 2 independent chains
#pragma unroll 8
    for (int k2 = 0; k2 < 128; ++k2) {
        union { unsigned v; f16 h[2]; } pr;
        pr.v = ldsT[(k2 << 6) + l];
        float a0 = (float)pr.h[0], a1 = (float)pr.h[1];
        float2 c0 = *(const float2*)(cpa + (k2 << 1));
        float2 u0 = *(const float2*)(ua + (k2 << 1));
        accx += gelu_f(a0 + c0.x) * u0.x;
        accy += gelu_f(a1 + c0.y) * u0.y;
    }
    float s0 = sv[tb0];
    int op = ((b << 8) + (pg << 6) + l) * TS;
    out[op + t0] = 1.f / (1.f + __expf(-(accx + accy + s0)));
}

// ---------------------------------------------------------------------------
// Launcher
// ---------------------------------------------------------------------------
extern "C" void kernel_launch(void* const* d_in, const int* in_sizes, int n_in,
                              void* d_out, int out_size, void* d_ws, size_t ws_size,
                              hipStream_t stream)
{
    (void)in_sizes; (void)n_in; (void)out_size;
    const float* patches   = (const float*)d_in[0];
    const int*   tokens    = (const int*)  d_in[1];
    const float* embedding = (const float*)d_in[2];
    const float* pos_emb   = (const float*)d_in[3];
    const float* in_proj_w = (const float*)d_in[4];
    const float* in_proj_b = (const float*)d_in[5];
    const float* out_proj_w= (const float*)d_in[6];
    const float* out_proj_b= (const float*)d_in[7];
    const float* lin1_w    = (const float*)d_in[8];
    const float* lin1_b    = (const float*)d_in[9];
    const float* lin2_w    = (const float*)d_in[10];
    const float* lin2_b    = (const float*)d_in[11];
    const float* ln1_g     = (const float*)d_in[12];
    const float* ln1_b     = (const float*)d_in[13];
    const float* ln2_g     = (const float*)d_in[14];
    const float* ln2_b     = (const float*)d_in[15];
    const float* fus_w1    = (const float*)d_in[16];
    const float* fus_b1    = (const float*)d_in[17];
    const float* fus_w2    = (const float*)d_in[18];
    const float* fus_b2    = (const float*)d_in[19];
    const float* cls_w     = (const float*)d_in[20];
    const float* cls_b     = (const float*)d_in[21];

    if (ws_size < (size_t)WS_FLOATS * 4) return;

    float* ws   = (float*)d_ws;
    f16*   embh = (f16*)(ws + OFF_EMBH);
    float* emb  = ws + OFF_EMB;           // dead (kept for layout stability)
    f16*   qkvh = (f16*)(ws + OFF_QKVH);
    f16*   x1p  = (f16*)(ws + OFF_X1);    // pre-LN attn-block out (f16)
    f16*   x1h  = (f16*)(ws + OFF_X1H);   // ln1 out (f16)
    f16*   pph  = (f16*)(ws + OFF_X1H);   // aliases x1h head (x1h dead after ln2)
    f16*   h1p  = (f16*)(ws + OFF_H1);    // pre-LN ffn out (f16)
    float* big  = ws + OFF_BIG;
    f16*   ao0h = (f16*)big;              // head; dead after out-proj0
    f16*   ff1h = (f16*)big;              // spans ALL of big; dead after lin2
    f16*   kv1h = (f16*)big;              // head; dead after attn1
    f16*   ao1h = (f16*)(big + BT_AO1H);
    float* x2   = big + BT_X2;
    f16*   x2h  = (f16*)(big + BT_X2H);
    f16*   ff2h = (f16*)(big + BT_FF2H);
    f16*   h1h  = (f16*)(big + BT_H1H);   // ln2 out (f16): kv/attn1/ln-x2 res
    float* ctx  = ws + OFF_CTX;           // dedicated; rows 0..31 zeroed by prep
    float* cpb  = ws + OFF_CPB;
    float* u    = ws + OFF_U;
    float* svec = ws + OFF_S;
    f16*   wqkvh= (f16*)(ws + OFF_WQKVH);
    f16*   wq1h = (f16*)(ws + OFF_WQ1H);
    f16*   kvwh = (f16*)(ws + OFF_KVWH);
    f16*   woh  = (f16*)(ws + OFF_WOH);
    f16*   woh1 = (f16*)(ws + OFF_WOH1);
    f16*   l1wh = (f16*)(ws + OFF_L1WH);
    f16*   l1wh1= (f16*)(ws + OFF_L1WH1);
    f16*   l2wh = (f16*)(ws + OFF_L2WH);
    f16*   l2wh1= (f16*)(ws + OFF_L2WH1);
    f16*   w1ph = (f16*)(ws + OFF_W1PH);
    f16*   w1ch = (f16*)(ws + OFF_W1CH);
    f16*   fw2th= (f16*)(ws + OFF_FW2TH);
    f16*   cwgh = (f16*)(ws + OFF_CWGH);
    int*   map1 = (int*)(ws + OFF_MAP);
    int*   map2 = map1 + NTOK;

    prep_kernel<<<10050, 256, 0, stream>>>(
        tokens, embedding, pos_emb, in_proj_w, out_proj_w, lin1_w, lin2_w,
        fus_w1, fus_w2, cls_w, cls_b, fus_b2,
        emb, embh, wqkvh, wq1h, kvwh, woh, woh1, l1wh, l1wh1, l2wh, l2wh1,
        w1ph, w1ch, fw2th, cwgh, svec, ctx, map1, map2);

    // u = cwg @ fw2t^T : M=1280(20x64), N=256(2), K=256 (u dedicated — safe early)
    gemm_x<64, 3, f16, false, false><<<dim3(2, 20), 256, 0, stream>>>(
        cwgh, DM, fw2th, DM, nullptr, u, DM, DM);

    // ---- Layer 0 ----
    gemm_x<64, 3, f16, false, true><<<dim3(6, 20), 256, 0, stream>>>(
        embh, DM, wqkvh, DM, in_proj_b, qkvh, 768, DM);
    attn0_kernel<<<NQ2, 256, 0, stream>>>(qkvh, ao0h);
    // out-proj0 -> x1p (f16 pre-LN); BM=128 (r6)
    gemm_x<128, 2, f16, false, true><<<dim3(2, 195), 256, 0, stream>>>(
        ao0h, DM, woh, DM, out_proj_b, x1p, DM, DM);
    // ln1: x1h = LN(x1p + embh[map1])
    ln_k<true, true><<<6240, 256, 0, stream>>>(
        x1p, embh, map1, ln1_g, ln1_b, NTOK, x1h, nullptr);
    gemm_x<128, 2, f16, true, true><<<dim3(8, 195), 256, 0, stream>>>(
        x1h, DM, l1wh, DM, lin1_b, ff1h, DFF, DM);
    // lin2 -> h1p (f16 pre-LN); BM=128 (r6)
    gemm_x<128, 2, f16, false, true><<<dim3(2, 195), 256, 0, stream>>>(
        ff1h, DFF, l2wh, DFF, lin2_b, h1p, DM, DFF);
    // ln2: h1h = LN(h1p + x1h)   (h1h in big tail; ff1h dead now)
    ln_k<true, true><<<6240, 256, 0, stream>>>(
        h1p, x1h, nullptr, ln2_g, ln2_b, NTOK, h1h, nullptr);

    // pp: M=8192(128x64), N=256(2), K=384 (x1h head free AFTER ln2 -> pph)
    gemm_x<64, 1, float, false, true><<<dim3(2, 128), 256, 0, stream>>>(
        patches, DINO, w1ph, DINO, nullptr, pph, DM, DINO);

    // ---- Layer 1 ----
    // K/V: A = h1h f16 async, N=512(4) -> kv1h (big head; disjoint from h1h tail)
    gemm_x<128, 2, f16, false, true><<<dim3(4, 195), 256, 0, stream>>>(
        h1h, DM, kvwh, DM, in_proj_b + 768 + 256, kv1h, 512, DM);
    attn1_kernel<<<NQ2, 256, 0, stream>>>(
        h1h, kv1h, wq1h, in_proj_b + 768, ao1h);
    // out-proj1 (MFMA, M padded to 1280; pad rows garbage, never read)
    gemm_x<64, 3, f16, false, false><<<dim3(2, 20), 256, 0, stream>>>(
        ao1h, DM, woh1, DM, out_proj_b + DM, x2, DM, DM);
    // ln(x2): res = h1h[map2] (f16); writes x2 (f32, residual for ln-ctx) + x2h
    ln_k<false, true><<<312, 256, 0, stream>>>(
        x2, h1h, map2, ln1_g + DM, ln1_b + DM, NQ2, x2h, x2);
    gemm_x<64, 3, f16, true, true><<<dim3(8, 20), 256, 0, stream>>>(
        x2h, DM, l1wh1, DM, lin1_b + DFF, ff2h, DFF, DM);
    // pad rows spill 8192 floats into cpb head; cpb-gemm rewrites cpb below
    gemm_x<64, 3, f16, false, false><<<dim3(2, 20), 256, 0, stream>>>(
        ff2h, DFF, l2wh1, DFF, lin2_b + DM, ctx + BB * DM, DM, DFF);
    // ln(ctx): res = x2 (f32); f32 in-place (cpb-gemm reads ctx as float)
    ln_k<false, false><<<312, 256, 0, stream>>>(
        ctx + BB * DM, x2, nullptr, ln2_g + DM, ln2_b + DM, NQ2, nullptr,
        ctx + BB * DM);

    // cpb = ctx @ w1c^T + fus_b1 : M=1280(20x64), N=256(2), K=256
    gemm_x<64, 1, float, false, false><<<dim3(2, 20), 256, 0, stream>>>(
        ctx, DM, w1ch, DM, fus_b1, cpb, DM, DM);

    final_out<<<640, 512, 0, stream>>>(pph, cpb, u, svec, (float*)d_out);
}